// Round 9
// baseline (518.040 us; speedup 1.0000x reference)
//
#include <hip/hip_runtime.h>

#define D 128
#define NB 4
#define BM2 256
#define SCAN_B 1024

typedef unsigned short u16;
typedef unsigned int u32;
using bf16x8 = __attribute__((ext_vector_type(8))) short;
using f32x4  = __attribute__((ext_vector_type(4))) float;

__device__ __forceinline__ float bf2f(u16 u) {
    union { u32 i; float f; } v; v.i = ((u32)u) << 16; return v.f;
}
__device__ __forceinline__ u16 f2bf(float f) {
    union { float ff; u32 i; } v; v.ff = f;
    u32 r = v.i + 0x7fffu + ((v.i >> 16) & 1u);   // RNE
    return (u16)(r >> 16);
}

// async 16B global -> LDS (wave-uniform lds base; lane i writes base + i*16)
__device__ __forceinline__ void async16(void* lds, const void* g) {
    __builtin_amdgcn_global_load_lds(
        (const __attribute__((address_space(1))) unsigned int*)g,
        (__attribute__((address_space(3))) unsigned int*)lds,
        16, 0, 0);
}

// -------------------- CSR build --------------------

__global__ __launch_bounds__(256) void degree_int_kernel(const int* __restrict__ dst,
                                                         int* __restrict__ deg, int E) {
    int e = blockIdx.x * 256 + threadIdx.x;
    if (e < E) atomicAdd(&deg[dst[e]], 1);
}

__global__ __launch_bounds__(256) void scan1_kernel(const int* __restrict__ deg,
                                                    int* __restrict__ row_start,
                                                    int* __restrict__ bsum, int n) {
    __shared__ int tsum[256];
    int base = blockIdx.x * SCAN_B;
    int t = threadIdx.x;
    int v[4];
    int s = 0;
#pragma unroll
    for (int i = 0; i < 4; ++i) {
        int idx = base + t * 4 + i;
        v[i] = (idx < n) ? deg[idx] : 0;
        s += v[i];
    }
    tsum[t] = s;
    __syncthreads();
    for (int off = 1; off < 256; off <<= 1) {
        int x = (t >= off) ? tsum[t - off] : 0;
        __syncthreads();
        tsum[t] += x;
        __syncthreads();
    }
    int run = tsum[t] - s;
#pragma unroll
    for (int i = 0; i < 4; ++i) {
        int idx = base + t * 4 + i;
        if (idx < n) row_start[idx] = run;
        run += v[i];
    }
    if (t == 255) bsum[blockIdx.x] = tsum[255];
}

__global__ __launch_bounds__(256) void scan2_kernel(int* __restrict__ bsum, int nb) {
    __shared__ int buf[256];
    __shared__ int carry_s;
    if (threadIdx.x == 0) carry_s = 0;
    __syncthreads();
    for (int base = 0; base < nb; base += 256) {
        int i = base + threadIdx.x;
        int v = (i < nb) ? bsum[i] : 0;
        buf[threadIdx.x] = v;
        __syncthreads();
        for (int off = 1; off < 256; off <<= 1) {
            int x = (threadIdx.x >= (unsigned)off) ? buf[threadIdx.x - off] : 0;
            __syncthreads();
            buf[threadIdx.x] += x;
            __syncthreads();
        }
        if (i < nb) bsum[i] = carry_s + buf[threadIdx.x] - v;
        __syncthreads();
        if (threadIdx.x == 0) carry_s += buf[255];
        __syncthreads();
    }
}

__global__ __launch_bounds__(256) void scan3_kernel(const int* __restrict__ deg,
                                                    const int* __restrict__ bsum,
                                                    int* __restrict__ row_start,
                                                    float* __restrict__ inv, int n, int E) {
    int i = blockIdx.x * 256 + threadIdx.x;
    if (i < n) {
        row_start[i] += bsum[i >> 10];
        inv[i] = 1.0f / fmaxf((float)deg[i], 1.0f);
    }
    if (i == 0) row_start[n] = E;
}

// fill: CSR permutation only — ONE scattered 8B store per edge (src, eid packed)
__global__ __launch_bounds__(256) void fill_kernel(
    const int* __restrict__ src, const int* __restrict__ dst,
    const int* __restrict__ row_start, int* __restrict__ fill,
    int2* __restrict__ csr_se, int E)
{
    int e = blockIdx.x * 256 + threadIdx.x;
    if (e >= E) return;
    int d0 = dst[e];
    int pos = row_start[d0] + atomicAdd(&fill[d0], 1);
    csr_se[pos] = make_int2(src[e], e);
}

// coef: linear read of csr_se, random 4B reads (L2-resident), COALESCED write
__global__ __launch_bounds__(256) void coef_kernel(
    const int2* __restrict__ csr_se, const int* __restrict__ etype,
    const float* __restrict__ norm, const float* __restrict__ att,
    float4* __restrict__ csr_coef, int E)
{
    int p = blockIdx.x * 256 + threadIdx.x;
    if (p >= E) return;
    int e = csr_se[p].y;
    float nm = norm[e];
    float4 a = ((const float4*)att)[etype[e]];
    csr_coef[p] = make_float4(a.x * nm, a.y * nm, a.z * nm, a.w * nm);
}

// -------------------- gather emb -> bf16 x0 --------------------

__global__ __launch_bounds__(256) void tobf_gather_kernel(const int* __restrict__ entity,
                                                          const float* __restrict__ emb,
                                                          u16* __restrict__ xbf, int n) {
    int idx = blockIdx.x * 256 + threadIdx.x;
    if (idx >= n * 32) return;
    int row = idx >> 5, c = idx & 31;
    float4 v = ((const float4*)emb)[(size_t)entity[row] * 32 + c];
    ushort4 o;
    o.x = f2bf(v.x); o.y = f2bf(v.y); o.z = f2bf(v.z); o.w = f2bf(v.w);
    ((ushort4*)xbf)[idx] = o;
}

// -------------------- CSR aggregation (8x/4x unrolled gather MLP) ----------
#define AGG_BODY(UJ)                                                            \
    {                                                                           \
        float4 c = c_[UJ];                                                      \
        float4 xv;                                                              \
        xv.x = bf2f(u_[UJ].x); xv.y = bf2f(u_[UJ].y);                           \
        xv.z = bf2f(u_[UJ].z); xv.w = bf2f(u_[UJ].w);                           \
        z0.x += c.x * xv.x; z0.y += c.x * xv.y; z0.z += c.x * xv.z; z0.w += c.x * xv.w; \
        z1.x += c.y * xv.x; z1.y += c.y * xv.y; z1.z += c.y * xv.z; z1.w += c.y * xv.w; \
        z2.x += c.z * xv.x; z2.y += c.z * xv.y; z2.z += c.z * xv.z; z2.w += c.z * xv.w; \
        z3.x += c.w * xv.x; z3.y += c.w * xv.y; z3.z += c.w * xv.z; z3.w += c.w * xv.w; \
    }

__global__ __launch_bounds__(256) void agg_kernel(
    const int* __restrict__ row_start, const int* __restrict__ deg,
    const float* __restrict__ inv, const int2* __restrict__ csr_se,
    const float4* __restrict__ csr_coef, const u16* __restrict__ xbf,
    u16* __restrict__ Zbf, int n)
{
    int nd = blockIdx.x * 8 + (threadIdx.x >> 5);
    if (nd >= n) return;
    int q = threadIdx.x & 31;
    int s0 = row_start[nd];
    int dg = deg[nd];
    float4 z0 = make_float4(0.f,0.f,0.f,0.f), z1 = z0, z2 = z0, z3 = z0;

    int i = 0;
    for (; i + 8 <= dg; i += 8) {
        int s_[8]; float4 c_[8]; ushort4 u_[8];
#pragma unroll
        for (int j = 0; j < 8; ++j) s_[j] = csr_se[s0 + i + j].x;
#pragma unroll
        for (int j = 0; j < 8; ++j) c_[j] = csr_coef[s0 + i + j];
#pragma unroll
        for (int j = 0; j < 8; ++j) u_[j] = ((const ushort4*)xbf)[(size_t)s_[j] * 32 + q];
#pragma unroll
        for (int j = 0; j < 8; ++j) AGG_BODY(j)
    }
    for (; i + 4 <= dg; i += 4) {
        int s_[4]; float4 c_[4]; ushort4 u_[4];
#pragma unroll
        for (int j = 0; j < 4; ++j) s_[j] = csr_se[s0 + i + j].x;
#pragma unroll
        for (int j = 0; j < 4; ++j) c_[j] = csr_coef[s0 + i + j];
#pragma unroll
        for (int j = 0; j < 4; ++j) u_[j] = ((const ushort4*)xbf)[(size_t)s_[j] * 32 + q];
#pragma unroll
        for (int j = 0; j < 4; ++j) AGG_BODY(j)
    }
    for (; i < dg; ++i) {
        int s_[1]; float4 c_[1]; ushort4 u_[1];
        s_[0] = csr_se[s0 + i].x;
        c_[0] = csr_coef[s0 + i];
        u_[0] = ((const ushort4*)xbf)[(size_t)s_[0] * 32 + q];
        AGG_BODY(0)
    }

    float iv = inv[nd];
    ushort4* zp = ((ushort4*)Zbf) + (size_t)nd * 128;
    ushort4 o;
    o.x = f2bf(z0.x * iv); o.y = f2bf(z0.y * iv); o.z = f2bf(z0.z * iv); o.w = f2bf(z0.w * iv);
    zp[q] = o;
    o.x = f2bf(z1.x * iv); o.y = f2bf(z1.y * iv); o.z = f2bf(z1.z * iv); o.w = f2bf(z1.w * iv);
    zp[32 + q] = o;
    o.x = f2bf(z2.x * iv); o.y = f2bf(z2.y * iv); o.z = f2bf(z2.z * iv); o.w = f2bf(z2.w * iv);
    zp[64 + q] = o;
    o.x = f2bf(z3.x * iv); o.y = f2bf(z3.y * iv); o.z = f2bf(z3.z * iv); o.w = f2bf(z3.w * iv);
    zp[96 + q] = o;
}

// -------------------- weight prep: transpose + hi/lo bf16 split --------------------
__global__ __launch_bounds__(256) void wprep_kernel(
    const float* __restrict__ basis, const float* __restrict__ root,
    u16* __restrict__ Wt)
{
    int idx = blockIdx.x * 256 + threadIdx.x;  // over 640*128
    if (idx >= 640 * 128) return;
    int k = idx >> 7, nn = idx & 127;
    float w = (k < 512) ? basis[(size_t)k * 128 + nn] : root[(size_t)(k - 512) * 128 + nn];
    u16 hi = f2bf(w);
    float lo = w - bf2f(hi);
    Wt[(size_t)nn * 1280 + k] = hi;
    Wt[(size_t)nn * 1280 + 640 + k] = f2bf(lo);
}

// -------------------- MFMA layer GEMM (256x128 tile, 8 waves) --------------------
// out[M][128] = [Zbf | xbf](M x 640 bf16) @ W(640 x 128, hi+lo bf16) + bias
// K-loop: 10 chunks of 64; per chunk stage A + B_hi + B_lo, then A fragments
// are read ONCE per kh and run against both B_hi and B_lo (register reuse).
__global__ __launch_bounds__(512) void mfma_gemm_kernel(
    const u16* __restrict__ Zbf, const u16* __restrict__ xbf,
    const u16* __restrict__ Wt, const float* __restrict__ bias,
    int relu, int write_bf, u16* __restrict__ obf, float* __restrict__ of32, int n)
{
    __shared__ u16 As[BM2 * 64];    // 32 KB
    __shared__ u16 Bh[128 * 64];    // 16 KB (hi weights)
    __shared__ u16 Bl[128 * 64];    // 16 KB (lo weights)

    const int tid  = threadIdx.x;
    const int row0 = blockIdx.x * BM2;
    const int lane = tid & 63;
    const int w    = tid >> 6;        // 0..7
    const int wr   = (w >> 1) * 64;   // 0,64,128,192
    const int wc   = (w & 1) * 64;    // 0,64
    const int lr   = lane & 15;
    const int lk   = lane >> 4;

    const int srow = lane >> 3;                       // r & 7 for staging
    const int sswz = ((lane & 7) * 16) ^ (srow << 4); // swizzled byte within row

    f32x4 zero = {0.f, 0.f, 0.f, 0.f};
    f32x4 acc[4][4];
#pragma unroll
    for (int mi = 0; mi < 4; ++mi)
#pragma unroll
        for (int ni = 0; ni < 4; ++ni) acc[mi][ni] = zero;

    for (int c = 0; c < 10; ++c) {
        const int wk = c * 64;
        __syncthreads();
        // stage A: 256 rows x 128B; wave w rows 32w..32w+31
#pragma unroll
        for (int j = 0; j < 4; ++j) {
            int r    = (w << 5) + (j << 3) + srow;
            int grow = row0 + r;
            const u16* gp = (c < 8)
                ? (Zbf + (size_t)grow * 512 + wk)
                : (xbf + (size_t)grow * 128 + (c - 8) * 64);
            async16((char*)As + (((w << 5) + (j << 3)) << 7),
                    (const char*)gp + sswz);
        }
        // stage B_hi and B_lo: 128 rows x 128B each; wave w rows 16w..16w+15
#pragma unroll
        for (int j = 0; j < 2; ++j) {
            int rr = (w << 4) + (j << 3) + srow;
            const u16* gp = Wt + (size_t)rr * 1280 + wk;
            async16((char*)Bh + (((w << 4) + (j << 3)) << 7),
                    (const char*)gp + sswz);
            async16((char*)Bl + (((w << 4) + (j << 3)) << 7),
                    (const char*)(gp + 640) + sswz);
        }
        __syncthreads();   // compiler drains vmcnt before barrier -> LDS ready

#pragma unroll
        for (int kh = 0; kh < 2; ++kh) {
            const int kb = (kh * 64 + lk * 16) ^ ((lr & 7) << 4);
            bf16x8 af[4], bh[4], bl[4];
#pragma unroll
            for (int mi = 0; mi < 4; ++mi)
                af[mi] = *(const bf16x8*)((const char*)As + ((wr + mi * 16 + lr) << 7) + kb);
#pragma unroll
            for (int ni = 0; ni < 4; ++ni)
                bh[ni] = *(const bf16x8*)((const char*)Bh + ((wc + ni * 16 + lr) << 7) + kb);
#pragma unroll
            for (int mi = 0; mi < 4; ++mi)
#pragma unroll
                for (int ni = 0; ni < 4; ++ni)
                    acc[mi][ni] = __builtin_amdgcn_mfma_f32_16x16x32_bf16(
                        af[mi], bh[ni], acc[mi][ni], 0, 0, 0);
#pragma unroll
            for (int ni = 0; ni < 4; ++ni)
                bl[ni] = *(const bf16x8*)((const char*)Bl + ((wc + ni * 16 + lr) << 7) + kb);
#pragma unroll
            for (int mi = 0; mi < 4; ++mi)
#pragma unroll
                for (int ni = 0; ni < 4; ++ni)
                    acc[mi][ni] = __builtin_amdgcn_mfma_f32_16x16x32_bf16(
                        af[mi], bl[ni], acc[mi][ni], 0, 0, 0);
        }
    }

    // epilogue: C/D layout col = lane&15, row = (lane>>4)*4 + reg
#pragma unroll
    for (int ni = 0; ni < 4; ++ni) {
        int col = wc + ni * 16 + lr;
        float bv = bias[col];
#pragma unroll
        for (int mi = 0; mi < 4; ++mi) {
#pragma unroll
            for (int r = 0; r < 4; ++r) {
                int row = row0 + wr + mi * 16 + lk * 4 + r;
                if (row < n) {
                    float v = acc[mi][ni][r] + bv;
                    if (relu) v = fmaxf(v, 0.f);
                    if (write_bf) obf[(size_t)row * 128 + col] = f2bf(v);
                    else          of32[(size_t)row * 128 + col] = v;
                }
            }
        }
    }
}

// -------------------- launch --------------------

extern "C" void kernel_launch(void* const* d_in, const int* in_sizes, int n_in,
                              void* d_out, int out_size, void* d_ws, size_t ws_size,
                              hipStream_t stream) {
    const int*   entity     = (const int*)d_in[0];
    const int*   edge_index = (const int*)d_in[1];
    const int*   edge_type  = (const int*)d_in[2];
    const float* edge_norm  = (const float*)d_in[3];
    const float* emb        = (const float*)d_in[4];
    const float* basis1     = (const float*)d_in[5];
    const float* att1       = (const float*)d_in[6];
    const float* root1      = (const float*)d_in[7];
    const float* bias1      = (const float*)d_in[8];
    const float* basis2     = (const float*)d_in[9];
    const float* att2       = (const float*)d_in[10];
    const float* root2      = (const float*)d_in[11];
    const float* bias2      = (const float*)d_in[12];
    float* out = (float*)d_out;

    const int N = in_sizes[0];
    const int E = in_sizes[2];
    const int* src = edge_index;
    const int* dst = edge_index + E;

    size_t ND = (size_t)N * D;
    char* wp = (char*)d_ws;
    int nb = (N + SCAN_B - 1) / SCAN_B;

    size_t off = 0;
    u16*    Zbf      = (u16*)(wp + off);   off += ND * 8;            // N*512 bf16
    u16*    xbf0     = (u16*)(wp + off);   off += ND * 2;            // N*128 bf16
    u16*    Wt       = (u16*)(wp + off);   off += (size_t)128 * 1280 * 2;
    float4* csr_coef = (float4*)(wp + off); off += (size_t)E * 16;
    int2*   csr_se   = (int2*)(wp + off);  off += (size_t)E * 8;
    int*    deg      = (int*)(wp + off);   off += (size_t)N * 4;
    int*    fill     = (int*)(wp + off);   off += (size_t)N * 4;
    float*  inv      = (float*)(wp + off); off += (size_t)N * 4;
    int*    row_start= (int*)(wp + off);   off += (size_t)(N + 1) * 4;
    int*    bsum     = (int*)(wp + off);   off += (size_t)(nb + 1) * 4;
    size_t need = off;

    if (ws_size < need) {
        hipMemsetAsync(d_out, 0, (size_t)out_size * sizeof(float), stream);
        return;
    }

    u16* xbf1 = (u16*)d_out;   // bf16 scratch inside d_out; overwritten by final fp32 GEMM

    int eblk = (E + 255) / 256;
    int ablk = (N + 7) / 8;
    int gblk = (N * 32 + 255) / 256;
    int mblk = (N + BM2 - 1) / BM2;
    int wblk = (640 * 128 + 255) / 256;
    int nblk256 = (N + 255) / 256;

    // ---- CSR build (once) ----
    hipMemsetAsync(deg, 0, (size_t)N * 4, stream);
    degree_int_kernel<<<eblk, 256, 0, stream>>>(dst, deg, E);
    scan1_kernel<<<nb, 256, 0, stream>>>(deg, row_start, bsum, N);
    scan2_kernel<<<1, 256, 0, stream>>>(bsum, nb);
    scan3_kernel<<<nblk256, 256, 0, stream>>>(deg, bsum, row_start, inv, N, E);
    hipMemsetAsync(fill, 0, (size_t)N * 4, stream);
    fill_kernel<<<eblk, 256, 0, stream>>>(src, dst, row_start, fill, csr_se, E);
    coef_kernel<<<eblk, 256, 0, stream>>>(csr_se, edge_type, edge_norm, att1, csr_coef, E);
    tobf_gather_kernel<<<gblk, 256, 0, stream>>>(entity, emb, xbf0, N);
    wprep_kernel<<<wblk, 256, 0, stream>>>(basis1, root1, Wt);

    // ---- layer 1: xbf0 -> xbf1 ----
    agg_kernel<<<ablk, 256, 0, stream>>>(row_start, deg, inv, csr_se, csr_coef, xbf0, Zbf, N);
    mfma_gemm_kernel<<<mblk, 512, 0, stream>>>(Zbf, xbf0, Wt, bias1, 0, 1, xbf1, nullptr, N);

    // ---- layer 2: xbf1 -> xbf0 (relu) ----
    agg_kernel<<<ablk, 256, 0, stream>>>(row_start, deg, inv, csr_se, csr_coef, xbf1, Zbf, N);
    mfma_gemm_kernel<<<mblk, 512, 0, stream>>>(Zbf, xbf1, Wt, bias1, 1, 1, xbf0, nullptr, N);

    // ---- layer 3: new coef (att2) + new weights; xbf0 -> out (fp32) ----
    coef_kernel<<<eblk, 256, 0, stream>>>(csr_se, edge_type, edge_norm, att2, csr_coef, E);
    wprep_kernel<<<wblk, 256, 0, stream>>>(basis2, root2, Wt);
    agg_kernel<<<ablk, 256, 0, stream>>>(row_start, deg, inv, csr_se, csr_coef, xbf0, Zbf, N);
    mfma_gemm_kernel<<<mblk, 512, 0, stream>>>(Zbf, xbf0, Wt, bias2, 0, 0, nullptr, out, N);
}

// Round 10
// 508.435 us; speedup vs baseline: 1.0189x; 1.0189x over previous
//
#include <hip/hip_runtime.h>

#define D 128
#define NB 4
#define BMG 128
#define SCAN_B 1024

typedef unsigned short u16;
typedef unsigned int u32;
using bf16x8 = __attribute__((ext_vector_type(8))) short;
using f32x4  = __attribute__((ext_vector_type(4))) float;

__device__ __forceinline__ float bf2f(u16 u) {
    union { u32 i; float f; } v; v.i = ((u32)u) << 16; return v.f;
}
__device__ __forceinline__ u16 f2bf(float f) {
    union { float ff; u32 i; } v; v.ff = f;
    u32 r = v.i + 0x7fffu + ((v.i >> 16) & 1u);   // RNE
    return (u16)(r >> 16);
}

// async 16B global -> LDS (wave-uniform lds base; lane i writes base + i*16)
__device__ __forceinline__ void async16(void* lds, const void* g) {
    __builtin_amdgcn_global_load_lds(
        (const __attribute__((address_space(1))) unsigned int*)g,
        (__attribute__((address_space(3))) unsigned int*)lds,
        16, 0, 0);
}

// -------------------- CSR build --------------------

__global__ __launch_bounds__(256) void degree_int_kernel(const int* __restrict__ dst,
                                                         int* __restrict__ deg, int E) {
    int e = blockIdx.x * 256 + threadIdx.x;
    if (e < E) atomicAdd(&deg[dst[e]], 1);
}

__global__ __launch_bounds__(256) void scan1_kernel(const int* __restrict__ deg,
                                                    int* __restrict__ row_start,
                                                    int* __restrict__ bsum, int n) {
    __shared__ int tsum[256];
    int base = blockIdx.x * SCAN_B;
    int t = threadIdx.x;
    int v[4];
    int s = 0;
#pragma unroll
    for (int i = 0; i < 4; ++i) {
        int idx = base + t * 4 + i;
        v[i] = (idx < n) ? deg[idx] : 0;
        s += v[i];
    }
    tsum[t] = s;
    __syncthreads();
    for (int off = 1; off < 256; off <<= 1) {
        int x = (t >= off) ? tsum[t - off] : 0;
        __syncthreads();
        tsum[t] += x;
        __syncthreads();
    }
    int run = tsum[t] - s;
#pragma unroll
    for (int i = 0; i < 4; ++i) {
        int idx = base + t * 4 + i;
        if (idx < n) row_start[idx] = run;
        run += v[i];
    }
    if (t == 255) bsum[blockIdx.x] = tsum[255];
}

__global__ __launch_bounds__(256) void scan2_kernel(int* __restrict__ bsum, int nb) {
    __shared__ int buf[256];
    __shared__ int carry_s;
    if (threadIdx.x == 0) carry_s = 0;
    __syncthreads();
    for (int base = 0; base < nb; base += 256) {
        int i = base + threadIdx.x;
        int v = (i < nb) ? bsum[i] : 0;
        buf[threadIdx.x] = v;
        __syncthreads();
        for (int off = 1; off < 256; off <<= 1) {
            int x = (threadIdx.x >= (unsigned)off) ? buf[threadIdx.x - off] : 0;
            __syncthreads();
            buf[threadIdx.x] += x;
            __syncthreads();
        }
        if (i < nb) bsum[i] = carry_s + buf[threadIdx.x] - v;
        __syncthreads();
        if (threadIdx.x == 0) carry_s += buf[255];
        __syncthreads();
    }
}

__global__ __launch_bounds__(256) void scan3_kernel(const int* __restrict__ deg,
                                                    const int* __restrict__ bsum,
                                                    int* __restrict__ row_start,
                                                    float* __restrict__ inv, int n, int E) {
    int i = blockIdx.x * 256 + threadIdx.x;
    if (i < n) {
        row_start[i] += bsum[i >> 10];
        inv[i] = 1.0f / fmaxf((float)deg[i], 1.0f);
    }
    if (i == 0) row_start[n] = E;
}

// fill: CSR permutation only — ONE scattered 8B store per edge (src, eid packed)
__global__ __launch_bounds__(256) void fill_kernel(
    const int* __restrict__ src, const int* __restrict__ dst,
    const int* __restrict__ row_start, int* __restrict__ fill,
    int2* __restrict__ csr_se, int E)
{
    int e = blockIdx.x * 256 + threadIdx.x;
    if (e >= E) return;
    int d0 = dst[e];
    int pos = row_start[d0] + atomicAdd(&fill[d0], 1);
    csr_se[pos] = make_int2(src[e], e);
}

// coef: linear read of csr_se, random 4B reads (L2-resident), COALESCED write
__global__ __launch_bounds__(256) void coef_kernel(
    const int2* __restrict__ csr_se, const int* __restrict__ etype,
    const float* __restrict__ norm, const float* __restrict__ att,
    float4* __restrict__ csr_coef, int E)
{
    int p = blockIdx.x * 256 + threadIdx.x;
    if (p >= E) return;
    int e = csr_se[p].y;
    float nm = norm[e];
    float4 a = ((const float4*)att)[etype[e]];
    csr_coef[p] = make_float4(a.x * nm, a.y * nm, a.z * nm, a.w * nm);
}

// -------------------- gather emb -> bf16 x0 --------------------

__global__ __launch_bounds__(256) void tobf_gather_kernel(const int* __restrict__ entity,
                                                          const float* __restrict__ emb,
                                                          u16* __restrict__ xbf, int n) {
    int idx = blockIdx.x * 256 + threadIdx.x;
    if (idx >= n * 32) return;
    int row = idx >> 5, c = idx & 31;
    float4 v = ((const float4*)emb)[(size_t)entity[row] * 32 + c];
    ushort4 o;
    o.x = f2bf(v.x); o.y = f2bf(v.y); o.z = f2bf(v.z); o.w = f2bf(v.w);
    ((ushort4*)xbf)[idx] = o;
}

// -------------------- CSR aggregation (8x/4x unrolled gather MLP) ----------
#define AGG_BODY(UJ)                                                            \
    {                                                                           \
        float4 c = c_[UJ];                                                      \
        float4 xv;                                                              \
        xv.x = bf2f(u_[UJ].x); xv.y = bf2f(u_[UJ].y);                           \
        xv.z = bf2f(u_[UJ].z); xv.w = bf2f(u_[UJ].w);                           \
        z0.x += c.x * xv.x; z0.y += c.x * xv.y; z0.z += c.x * xv.z; z0.w += c.x * xv.w; \
        z1.x += c.y * xv.x; z1.y += c.y * xv.y; z1.z += c.y * xv.z; z1.w += c.y * xv.w; \
        z2.x += c.z * xv.x; z2.y += c.z * xv.y; z2.z += c.z * xv.z; z2.w += c.z * xv.w; \
        z3.x += c.w * xv.x; z3.y += c.w * xv.y; z3.z += c.w * xv.z; z3.w += c.w * xv.w; \
    }

__global__ __launch_bounds__(256) void agg_kernel(
    const int* __restrict__ row_start, const int* __restrict__ deg,
    const float* __restrict__ inv, const int2* __restrict__ csr_se,
    const float4* __restrict__ csr_coef, const u16* __restrict__ xbf,
    u16* __restrict__ Zbf, int n)
{
    int nd = blockIdx.x * 8 + (threadIdx.x >> 5);
    if (nd >= n) return;
    int q = threadIdx.x & 31;
    int s0 = row_start[nd];
    int dg = deg[nd];
    float4 z0 = make_float4(0.f,0.f,0.f,0.f), z1 = z0, z2 = z0, z3 = z0;

    int i = 0;
    for (; i + 8 <= dg; i += 8) {
        int s_[8]; float4 c_[8]; ushort4 u_[8];
#pragma unroll
        for (int j = 0; j < 8; ++j) s_[j] = csr_se[s0 + i + j].x;
#pragma unroll
        for (int j = 0; j < 8; ++j) c_[j] = csr_coef[s0 + i + j];
#pragma unroll
        for (int j = 0; j < 8; ++j) u_[j] = ((const ushort4*)xbf)[(size_t)s_[j] * 32 + q];
#pragma unroll
        for (int j = 0; j < 8; ++j) AGG_BODY(j)
    }
    for (; i + 4 <= dg; i += 4) {
        int s_[4]; float4 c_[4]; ushort4 u_[4];
#pragma unroll
        for (int j = 0; j < 4; ++j) s_[j] = csr_se[s0 + i + j].x;
#pragma unroll
        for (int j = 0; j < 4; ++j) c_[j] = csr_coef[s0 + i + j];
#pragma unroll
        for (int j = 0; j < 4; ++j) u_[j] = ((const ushort4*)xbf)[(size_t)s_[j] * 32 + q];
#pragma unroll
        for (int j = 0; j < 4; ++j) AGG_BODY(j)
    }
    for (; i < dg; ++i) {
        int s_[1]; float4 c_[1]; ushort4 u_[1];
        s_[0] = csr_se[s0 + i].x;
        c_[0] = csr_coef[s0 + i];
        u_[0] = ((const ushort4*)xbf)[(size_t)s_[0] * 32 + q];
        AGG_BODY(0)
    }

    float iv = inv[nd];
    ushort4* zp = ((ushort4*)Zbf) + (size_t)nd * 128;
    ushort4 o;
    o.x = f2bf(z0.x * iv); o.y = f2bf(z0.y * iv); o.z = f2bf(z0.z * iv); o.w = f2bf(z0.w * iv);
    zp[q] = o;
    o.x = f2bf(z1.x * iv); o.y = f2bf(z1.y * iv); o.z = f2bf(z1.z * iv); o.w = f2bf(z1.w * iv);
    zp[32 + q] = o;
    o.x = f2bf(z2.x * iv); o.y = f2bf(z2.y * iv); o.z = f2bf(z2.z * iv); o.w = f2bf(z2.w * iv);
    zp[64 + q] = o;
    o.x = f2bf(z3.x * iv); o.y = f2bf(z3.y * iv); o.z = f2bf(z3.z * iv); o.w = f2bf(z3.w * iv);
    zp[96 + q] = o;
}

// -------------------- weight prep: transpose + hi/lo bf16 split --------------------
__global__ __launch_bounds__(256) void wprep_kernel(
    const float* __restrict__ basis, const float* __restrict__ root,
    u16* __restrict__ Wt)
{
    int idx = blockIdx.x * 256 + threadIdx.x;  // over 640*128
    if (idx >= 640 * 128) return;
    int k = idx >> 7, nn = idx & 127;
    float w = (k < 512) ? basis[(size_t)k * 128 + nn] : root[(size_t)(k - 512) * 128 + nn];
    u16 hi = f2bf(w);
    float lo = w - bf2f(hi);
    Wt[(size_t)nn * 1280 + k] = hi;
    Wt[(size_t)nn * 1280 + 640 + k] = f2bf(lo);
}

// -------------------- MFMA layer GEMM (128x128 tile, 4 waves, 32KB LDS) ------
// out[M][128] = [Zbf | xbf](M x 640 bf16) @ W(640 x 128, hi+lo bf16) + bias
// 20 stages (hi/lo alternating); A staged on even stages only. Small LDS ->
// ~5 blocks/CU capacity so co-resident blocks hide each other's barrier drains.
__global__ __launch_bounds__(256) void mfma_gemm_kernel(
    const u16* __restrict__ Zbf, const u16* __restrict__ xbf,
    const u16* __restrict__ Wt, const float* __restrict__ bias,
    int relu, int write_bf, u16* __restrict__ obf, float* __restrict__ of32, int n)
{
    __shared__ u16 As[BMG * 64];   // 16 KB
    __shared__ u16 Bs[128 * 64];   // 16 KB (n-major)

    const int tid  = threadIdx.x;
    const int row0 = blockIdx.x * BMG;
    const int lane = tid & 63;
    const int w    = tid >> 6;        // 0..3
    const int wr   = (w >> 1) * 64;   // 0,64
    const int wc   = (w & 1) * 64;    // 0,64
    const int lr   = lane & 15;
    const int lk   = lane >> 4;

    const int srow = lane >> 3;                       // r & 7 for staging
    const int sswz = ((lane & 7) * 16) ^ (srow << 4); // swizzled byte within row

    f32x4 zero = {0.f, 0.f, 0.f, 0.f};
    f32x4 acc[4][4];
#pragma unroll
    for (int mi = 0; mi < 4; ++mi)
#pragma unroll
        for (int ni = 0; ni < 4; ++ni) acc[mi][ni] = zero;

    for (int s = 0; s < 20; ++s) {
        const int ac = s >> 1;                    // A chunk 0..9
        const int wk = (s & 1) * 640 + ac * 64;   // Wt k-offset (hi then lo)
        __syncthreads();
        if ((s & 1) == 0) {
            // stage A: 128 rows x 128B; wave w rows 32w..32w+31, 4 instrs
#pragma unroll
            for (int j = 0; j < 4; ++j) {
                int r    = (w << 5) + (j << 3) + srow;
                int grow = row0 + r;
                const u16* gp = (ac < 8)
                    ? (Zbf + (size_t)grow * 512 + ac * 64)
                    : (xbf + (size_t)grow * 128 + (ac - 8) * 64);
                async16((char*)As + (((w << 5) + (j << 3)) << 7),
                        (const char*)gp + sswz);
            }
        }
        // stage B: 128 rows x 128B; wave w rows 32w..32w+31, 4 instrs
#pragma unroll
        for (int j = 0; j < 4; ++j) {
            int rr = (w << 5) + (j << 3) + srow;
            const u16* gp = Wt + (size_t)rr * 1280 + wk;
            async16((char*)Bs + (((w << 5) + (j << 3)) << 7),
                    (const char*)gp + sswz);
        }
        __syncthreads();   // compiler drains vmcnt before barrier -> LDS ready

#pragma unroll
        for (int kh = 0; kh < 2; ++kh) {
            const int kb = (kh * 64 + lk * 16) ^ ((lr & 7) << 4);
            bf16x8 af[4], bfr[4];
#pragma unroll
            for (int mi = 0; mi < 4; ++mi)
                af[mi] = *(const bf16x8*)((const char*)As + ((wr + mi * 16 + lr) << 7) + kb);
#pragma unroll
            for (int ni = 0; ni < 4; ++ni)
                bfr[ni] = *(const bf16x8*)((const char*)Bs + ((wc + ni * 16 + lr) << 7) + kb);
#pragma unroll
            for (int mi = 0; mi < 4; ++mi)
#pragma unroll
                for (int ni = 0; ni < 4; ++ni)
                    acc[mi][ni] = __builtin_amdgcn_mfma_f32_16x16x32_bf16(
                        af[mi], bfr[ni], acc[mi][ni], 0, 0, 0);
        }
    }

    // epilogue: C/D layout col = lane&15, row = (lane>>4)*4 + reg
#pragma unroll
    for (int ni = 0; ni < 4; ++ni) {
        int col = wc + ni * 16 + lr;
        float bv = bias[col];
#pragma unroll
        for (int mi = 0; mi < 4; ++mi) {
#pragma unroll
            for (int r = 0; r < 4; ++r) {
                int row = row0 + wr + mi * 16 + lk * 4 + r;
                if (row < n) {
                    float v = acc[mi][ni][r] + bv;
                    if (relu) v = fmaxf(v, 0.f);
                    if (write_bf) obf[(size_t)row * 128 + col] = f2bf(v);
                    else          of32[(size_t)row * 128 + col] = v;
                }
            }
        }
    }
}

// -------------------- launch --------------------

extern "C" void kernel_launch(void* const* d_in, const int* in_sizes, int n_in,
                              void* d_out, int out_size, void* d_ws, size_t ws_size,
                              hipStream_t stream) {
    const int*   entity     = (const int*)d_in[0];
    const int*   edge_index = (const int*)d_in[1];
    const int*   edge_type  = (const int*)d_in[2];
    const float* edge_norm  = (const float*)d_in[3];
    const float* emb        = (const float*)d_in[4];
    const float* basis1     = (const float*)d_in[5];
    const float* att1       = (const float*)d_in[6];
    const float* root1      = (const float*)d_in[7];
    const float* bias1      = (const float*)d_in[8];
    const float* basis2     = (const float*)d_in[9];
    const float* att2       = (const float*)d_in[10];
    const float* root2      = (const float*)d_in[11];
    const float* bias2      = (const float*)d_in[12];
    float* out = (float*)d_out;

    const int N = in_sizes[0];
    const int E = in_sizes[2];
    const int* src = edge_index;
    const int* dst = edge_index + E;

    size_t ND = (size_t)N * D;
    char* wp = (char*)d_ws;
    int nb = (N + SCAN_B - 1) / SCAN_B;

    size_t off = 0;
    u16*    Zbf      = (u16*)(wp + off);   off += ND * 8;            // N*512 bf16
    u16*    xbf0     = (u16*)(wp + off);   off += ND * 2;            // N*128 bf16
    u16*    Wt       = (u16*)(wp + off);   off += (size_t)128 * 1280 * 2;
    float4* csr_coef = (float4*)(wp + off); off += (size_t)E * 16;
    int2*   csr_se   = (int2*)(wp + off);  off += (size_t)E * 8;
    int*    deg      = (int*)(wp + off);   off += (size_t)N * 4;
    int*    fill     = (int*)(wp + off);   off += (size_t)N * 4;
    float*  inv      = (float*)(wp + off); off += (size_t)N * 4;
    int*    row_start= (int*)(wp + off);   off += (size_t)(N + 1) * 4;
    int*    bsum     = (int*)(wp + off);   off += (size_t)(nb + 1) * 4;
    size_t need = off;

    if (ws_size < need) {
        hipMemsetAsync(d_out, 0, (size_t)out_size * sizeof(float), stream);
        return;
    }

    u16* xbf1 = (u16*)d_out;   // bf16 scratch inside d_out; overwritten by final fp32 GEMM

    int eblk = (E + 255) / 256;
    int ablk = (N + 7) / 8;
    int gblk = (N * 32 + 255) / 256;
    int mblk = (N + BMG - 1) / BMG;
    int wblk = (640 * 128 + 255) / 256;
    int nblk256 = (N + 255) / 256;

    // ---- CSR build (once) ----
    hipMemsetAsync(deg, 0, (size_t)N * 4, stream);
    degree_int_kernel<<<eblk, 256, 0, stream>>>(dst, deg, E);
    scan1_kernel<<<nb, 256, 0, stream>>>(deg, row_start, bsum, N);
    scan2_kernel<<<1, 256, 0, stream>>>(bsum, nb);
    scan3_kernel<<<nblk256, 256, 0, stream>>>(deg, bsum, row_start, inv, N, E);
    hipMemsetAsync(fill, 0, (size_t)N * 4, stream);
    fill_kernel<<<eblk, 256, 0, stream>>>(src, dst, row_start, fill, csr_se, E);
    coef_kernel<<<eblk, 256, 0, stream>>>(csr_se, edge_type, edge_norm, att1, csr_coef, E);
    tobf_gather_kernel<<<gblk, 256, 0, stream>>>(entity, emb, xbf0, N);
    wprep_kernel<<<wblk, 256, 0, stream>>>(basis1, root1, Wt);

    // ---- layer 1: xbf0 -> xbf1 ----
    agg_kernel<<<ablk, 256, 0, stream>>>(row_start, deg, inv, csr_se, csr_coef, xbf0, Zbf, N);
    mfma_gemm_kernel<<<mblk, 256, 0, stream>>>(Zbf, xbf0, Wt, bias1, 0, 1, xbf1, nullptr, N);

    // ---- layer 2: xbf1 -> xbf0 (relu) ----
    agg_kernel<<<ablk, 256, 0, stream>>>(row_start, deg, inv, csr_se, csr_coef, xbf1, Zbf, N);
    mfma_gemm_kernel<<<mblk, 256, 0, stream>>>(Zbf, xbf1, Wt, bias1, 1, 1, xbf0, nullptr, N);

    // ---- layer 3: new coef (att2) + new weights; xbf0 -> out (fp32) ----
    coef_kernel<<<eblk, 256, 0, stream>>>(csr_se, edge_type, edge_norm, att2, csr_coef, E);
    wprep_kernel<<<wblk, 256, 0, stream>>>(basis2, root2, Wt);
    agg_kernel<<<ablk, 256, 0, stream>>>(row_start, deg, inv, csr_se, csr_coef, xbf0, Zbf, N);
    mfma_gemm_kernel<<<mblk, 256, 0, stream>>>(Zbf, xbf0, Wt, bias2, 0, 0, nullptr, out, N);
}

// Round 11
// 506.098 us; speedup vs baseline: 1.0236x; 1.0046x over previous
//
#include <hip/hip_runtime.h>

#define D 128
#define NB 4
#define BMP 256
#define SCAN_B 1024

typedef unsigned short u16;
typedef unsigned int u32;
using bf16x8 = __attribute__((ext_vector_type(8))) short;
using f32x4  = __attribute__((ext_vector_type(4))) float;

__device__ __forceinline__ float bf2f(u16 u) {
    union { u32 i; float f; } v; v.i = ((u32)u) << 16; return v.f;
}
__device__ __forceinline__ u16 f2bf(float f) {
    union { float ff; u32 i; } v; v.ff = f;
    u32 r = v.i + 0x7fffu + ((v.i >> 16) & 1u);   // RNE
    return (u16)(r >> 16);
}

// async 16B global -> LDS (wave-uniform lds base; lane i writes base + i*16)
__device__ __forceinline__ void async16(void* lds, const void* g) {
    __builtin_amdgcn_global_load_lds(
        (const __attribute__((address_space(1))) unsigned int*)g,
        (__attribute__((address_space(3))) unsigned int*)lds,
        16, 0, 0);
}

// -------------------- CSR build --------------------

__global__ __launch_bounds__(256) void degree_int_kernel(const int* __restrict__ dst,
                                                         int* __restrict__ deg, int E) {
    int e = blockIdx.x * 256 + threadIdx.x;
    if (e < E) atomicAdd(&deg[dst[e]], 1);
}

__global__ __launch_bounds__(256) void scan1_kernel(const int* __restrict__ deg,
                                                    int* __restrict__ row_start,
                                                    int* __restrict__ bsum, int n) {
    __shared__ int tsum[256];
    int base = blockIdx.x * SCAN_B;
    int t = threadIdx.x;
    int v[4];
    int s = 0;
#pragma unroll
    for (int i = 0; i < 4; ++i) {
        int idx = base + t * 4 + i;
        v[i] = (idx < n) ? deg[idx] : 0;
        s += v[i];
    }
    tsum[t] = s;
    __syncthreads();
    for (int off = 1; off < 256; off <<= 1) {
        int x = (t >= off) ? tsum[t - off] : 0;
        __syncthreads();
        tsum[t] += x;
        __syncthreads();
    }
    int run = tsum[t] - s;
#pragma unroll
    for (int i = 0; i < 4; ++i) {
        int idx = base + t * 4 + i;
        if (idx < n) row_start[idx] = run;
        run += v[i];
    }
    if (t == 255) bsum[blockIdx.x] = tsum[255];
}

__global__ __launch_bounds__(256) void scan2_kernel(int* __restrict__ bsum, int nb) {
    __shared__ int buf[256];
    __shared__ int carry_s;
    if (threadIdx.x == 0) carry_s = 0;
    __syncthreads();
    for (int base = 0; base < nb; base += 256) {
        int i = base + threadIdx.x;
        int v = (i < nb) ? bsum[i] : 0;
        buf[threadIdx.x] = v;
        __syncthreads();
        for (int off = 1; off < 256; off <<= 1) {
            int x = (threadIdx.x >= (unsigned)off) ? buf[threadIdx.x - off] : 0;
            __syncthreads();
            buf[threadIdx.x] += x;
            __syncthreads();
        }
        if (i < nb) bsum[i] = carry_s + buf[threadIdx.x] - v;
        __syncthreads();
        if (threadIdx.x == 0) carry_s += buf[255];
        __syncthreads();
    }
}

__global__ __launch_bounds__(256) void scan3_kernel(const int* __restrict__ deg,
                                                    const int* __restrict__ bsum,
                                                    int* __restrict__ row_start,
                                                    float* __restrict__ inv, int n, int E) {
    int i = blockIdx.x * 256 + threadIdx.x;
    if (i < n) {
        row_start[i] += bsum[i >> 10];
        inv[i] = 1.0f / fmaxf((float)deg[i], 1.0f);
    }
    if (i == 0) row_start[n] = E;
}

// fill: CSR permutation only — ONE scattered 8B store per edge (src, eid packed)
__global__ __launch_bounds__(256) void fill_kernel(
    const int* __restrict__ src, const int* __restrict__ dst,
    const int* __restrict__ row_start, int* __restrict__ fill,
    int2* __restrict__ csr_se, int E)
{
    int e = blockIdx.x * 256 + threadIdx.x;
    if (e >= E) return;
    int d0 = dst[e];
    int pos = row_start[d0] + atomicAdd(&fill[d0], 1);
    csr_se[pos] = make_int2(src[e], e);
}

// coef: linear read of csr_se, random 4B reads (L2-resident), COALESCED write
__global__ __launch_bounds__(256) void coef_kernel(
    const int2* __restrict__ csr_se, const int* __restrict__ etype,
    const float* __restrict__ norm, const float* __restrict__ att,
    float4* __restrict__ csr_coef, int E)
{
    int p = blockIdx.x * 256 + threadIdx.x;
    if (p >= E) return;
    int e = csr_se[p].y;
    float nm = norm[e];
    float4 a = ((const float4*)att)[etype[e]];
    csr_coef[p] = make_float4(a.x * nm, a.y * nm, a.z * nm, a.w * nm);
}

// -------------------- gather emb -> bf16 x0 --------------------

__global__ __launch_bounds__(256) void tobf_gather_kernel(const int* __restrict__ entity,
                                                          const float* __restrict__ emb,
                                                          u16* __restrict__ xbf, int n) {
    int idx = blockIdx.x * 256 + threadIdx.x;
    if (idx >= n * 32) return;
    int row = idx >> 5, c = idx & 31;
    float4 v = ((const float4*)emb)[(size_t)entity[row] * 32 + c];
    ushort4 o;
    o.x = f2bf(v.x); o.y = f2bf(v.y); o.z = f2bf(v.z); o.w = f2bf(v.w);
    ((ushort4*)xbf)[idx] = o;
}

// -------------------- CSR aggregation (8x/4x unrolled gather MLP) ----------
#define AGG_BODY(UJ)                                                            \
    {                                                                           \
        float4 c = c_[UJ];                                                      \
        float4 xv;                                                              \
        xv.x = bf2f(u_[UJ].x); xv.y = bf2f(u_[UJ].y);                           \
        xv.z = bf2f(u_[UJ].z); xv.w = bf2f(u_[UJ].w);                           \
        z0.x += c.x * xv.x; z0.y += c.x * xv.y; z0.z += c.x * xv.z; z0.w += c.x * xv.w; \
        z1.x += c.y * xv.x; z1.y += c.y * xv.y; z1.z += c.y * xv.z; z1.w += c.y * xv.w; \
        z2.x += c.z * xv.x; z2.y += c.z * xv.y; z2.z += c.z * xv.z; z2.w += c.z * xv.w; \
        z3.x += c.w * xv.x; z3.y += c.w * xv.y; z3.z += c.w * xv.z; z3.w += c.w * xv.w; \
    }

__global__ __launch_bounds__(256) void agg_kernel(
    const int* __restrict__ row_start, const int* __restrict__ deg,
    const float* __restrict__ inv, const int2* __restrict__ csr_se,
    const float4* __restrict__ csr_coef, const u16* __restrict__ xbf,
    u16* __restrict__ Zbf, int n)
{
    int nd = blockIdx.x * 8 + (threadIdx.x >> 5);
    if (nd >= n) return;
    int q = threadIdx.x & 31;
    int s0 = row_start[nd];
    int dg = deg[nd];
    float4 z0 = make_float4(0.f,0.f,0.f,0.f), z1 = z0, z2 = z0, z3 = z0;

    int i = 0;
    for (; i + 8 <= dg; i += 8) {
        int s_[8]; float4 c_[8]; ushort4 u_[8];
#pragma unroll
        for (int j = 0; j < 8; ++j) s_[j] = csr_se[s0 + i + j].x;
#pragma unroll
        for (int j = 0; j < 8; ++j) c_[j] = csr_coef[s0 + i + j];
#pragma unroll
        for (int j = 0; j < 8; ++j) u_[j] = ((const ushort4*)xbf)[(size_t)s_[j] * 32 + q];
#pragma unroll
        for (int j = 0; j < 8; ++j) AGG_BODY(j)
    }
    for (; i + 4 <= dg; i += 4) {
        int s_[4]; float4 c_[4]; ushort4 u_[4];
#pragma unroll
        for (int j = 0; j < 4; ++j) s_[j] = csr_se[s0 + i + j].x;
#pragma unroll
        for (int j = 0; j < 4; ++j) c_[j] = csr_coef[s0 + i + j];
#pragma unroll
        for (int j = 0; j < 4; ++j) u_[j] = ((const ushort4*)xbf)[(size_t)s_[j] * 32 + q];
#pragma unroll
        for (int j = 0; j < 4; ++j) AGG_BODY(j)
    }
    for (; i < dg; ++i) {
        int s_[1]; float4 c_[1]; ushort4 u_[1];
        s_[0] = csr_se[s0 + i].x;
        c_[0] = csr_coef[s0 + i];
        u_[0] = ((const ushort4*)xbf)[(size_t)s_[0] * 32 + q];
        AGG_BODY(0)
    }

    float iv = inv[nd];
    ushort4* zp = ((ushort4*)Zbf) + (size_t)nd * 128;
    ushort4 o;
    o.x = f2bf(z0.x * iv); o.y = f2bf(z0.y * iv); o.z = f2bf(z0.z * iv); o.w = f2bf(z0.w * iv);
    zp[q] = o;
    o.x = f2bf(z1.x * iv); o.y = f2bf(z1.y * iv); o.z = f2bf(z1.z * iv); o.w = f2bf(z1.w * iv);
    zp[32 + q] = o;
    o.x = f2bf(z2.x * iv); o.y = f2bf(z2.y * iv); o.z = f2bf(z2.z * iv); o.w = f2bf(z2.w * iv);
    zp[64 + q] = o;
    o.x = f2bf(z3.x * iv); o.y = f2bf(z3.y * iv); o.z = f2bf(z3.z * iv); o.w = f2bf(z3.w * iv);
    zp[96 + q] = o;
}

// -------------------- weight prep: transpose + hi/lo bf16 split --------------------
__global__ __launch_bounds__(256) void wprep_kernel(
    const float* __restrict__ basis, const float* __restrict__ root,
    u16* __restrict__ Wt)
{
    int idx = blockIdx.x * 256 + threadIdx.x;  // over 640*128
    if (idx >= 640 * 128) return;
    int k = idx >> 7, nn = idx & 127;
    float w = (k < 512) ? basis[(size_t)k * 128 + nn] : root[(size_t)(k - 512) * 128 + nn];
    u16 hi = f2bf(w);
    float lo = w - bf2f(hi);
    Wt[(size_t)nn * 1280 + k] = hi;
    Wt[(size_t)nn * 1280 + 640 + k] = f2bf(lo);
}

// -------------------- MFMA layer GEMM: pipelined dbuf, counted vmcnt ---------
// out[M][128] = [Zbf | xbf](M x 640 bf16) @ W(640 x 128, hi+lo bf16) + bias
// 10 chunks of K=64. Chunk buffer = {A 256x128B, B 128x256B(hi|lo)} = 64 KB,
// double-buffered (128 KB LDS). STAGE(c+1) issued BEFORE waiting on chunk c;
// asm s_waitcnt vmcnt(8) leaves the 8 next-chunk ops in flight across the raw
// barrier (T3+T4). A-fragments read once per kh, reused for hi and lo MFMA.
__global__ __launch_bounds__(512) void mfma_gemm_kernel(
    const u16* __restrict__ Zbf, const u16* __restrict__ xbf,
    const u16* __restrict__ Wt, const float* __restrict__ bias,
    int relu, int write_bf, u16* __restrict__ obf, float* __restrict__ of32, int n)
{
    __shared__ u16 As[2][BMP * 64];    // 2 x 32 KB  (rows of 128B)
    __shared__ u16 Bs[2][128 * 128];   // 2 x 32 KB  (rows of 256B: hi|lo)

    const int tid  = threadIdx.x;
    const int row0 = blockIdx.x * BMP;
    const int lane = tid & 63;
    const int w    = tid >> 6;        // 0..7
    const int wr   = (w >> 1) * 64;   // 0,64,128,192
    const int wc   = (w & 1) * 64;    // 0,64
    const int lr   = lane & 15;
    const int lk   = lane >> 4;

    // A staging: 8 rows x 128B per instr
    const int srowA = lane >> 3;                          // 0..7
    const int sswzA = ((lane & 7) << 4) ^ (srowA << 4);   // swizzled byte in row
    // B staging: 4 rows x 256B per instr; half 0 = hi, half 1 = lo
    const int srowB = lane >> 4;                          // 0..3
    const int halfB = (lane >> 3) & 1;
    const int slotB = (lane & 7) << 4;                    // 16B slot in half

    f32x4 zero = {0.f, 0.f, 0.f, 0.f};
    f32x4 acc[4][4];
#pragma unroll
    for (int mi = 0; mi < 4; ++mi)
#pragma unroll
        for (int ni = 0; ni < 4; ++ni) acc[mi][ni] = zero;

    auto STAGE = [&](int c, int p) {
        // A: 4 instrs per wave (wave w covers rows 32w..32w+31)
#pragma unroll
        for (int j = 0; j < 4; ++j) {
            int r    = (w << 5) + (j << 3) + srowA;
            int grow = row0 + r;
            const char* gp = (c < 8)
                ? (const char*)(Zbf + (size_t)grow * 512 + c * 64)
                : (const char*)(xbf + (size_t)grow * 128 + (c - 8) * 64);
            async16((char*)&As[p][((w << 5) + (j << 3)) * 64], gp + sswzA);
        }
        // B: 4 instrs per wave (wave w covers rows 16w..16w+15)
#pragma unroll
        for (int j = 0; j < 4; ++j) {
            int rr = (w << 4) + (j << 2) + srowB;
            const char* gp = (const char*)Wt + (size_t)rr * 2560
                           + (halfB ? 1280 : 0) + c * 128
                           + (slotB ^ ((rr & 7) << 4));
            async16((char*)&Bs[p][((w << 4) + (j << 2)) * 128], gp);
        }
    };

    STAGE(0, 0);   // prologue: 8 vm ops in flight

    for (int c = 0; c < 10; ++c) {
        const int p = c & 1;
        if (c < 9) STAGE(c + 1, p ^ 1);
        __builtin_amdgcn_sched_barrier(0);
        if (c < 9) asm volatile("s_waitcnt vmcnt(8)" ::: "memory");
        else       asm volatile("s_waitcnt vmcnt(0)" ::: "memory");
        __builtin_amdgcn_sched_barrier(0);
        __builtin_amdgcn_s_barrier();
        __builtin_amdgcn_sched_barrier(0);

#pragma unroll
        for (int kh = 0; kh < 2; ++kh) {
            const int kb = ((kh * 4 + lk) << 4) ^ ((lr & 7) << 4);
            bf16x8 af[4], bh[4], bl[4];
#pragma unroll
            for (int mi = 0; mi < 4; ++mi)
                af[mi] = *(const bf16x8*)((const char*)&As[p][0] + (wr + mi * 16 + lr) * 128 + kb);
#pragma unroll
            for (int ni = 0; ni < 4; ++ni)
                bh[ni] = *(const bf16x8*)((const char*)&Bs[p][0] + (wc + ni * 16 + lr) * 256 + kb);
#pragma unroll
            for (int mi = 0; mi < 4; ++mi)
#pragma unroll
                for (int ni = 0; ni < 4; ++ni)
                    acc[mi][ni] = __builtin_amdgcn_mfma_f32_16x16x32_bf16(
                        af[mi], bh[ni], acc[mi][ni], 0, 0, 0);
#pragma unroll
            for (int ni = 0; ni < 4; ++ni)
                bl[ni] = *(const bf16x8*)((const char*)&Bs[p][0] + (wc + ni * 16 + lr) * 256 + 128 + kb);
#pragma unroll
            for (int mi = 0; mi < 4; ++mi)
#pragma unroll
                for (int ni = 0; ni < 4; ++ni)
                    acc[mi][ni] = __builtin_amdgcn_mfma_f32_16x16x32_bf16(
                        af[mi], bl[ni], acc[mi][ni], 0, 0, 0);
        }
        __builtin_amdgcn_sched_barrier(0);
        __builtin_amdgcn_s_barrier();
        __builtin_amdgcn_sched_barrier(0);
    }

    // epilogue: C/D layout col = lane&15, row = (lane>>4)*4 + reg
#pragma unroll
    for (int ni = 0; ni < 4; ++ni) {
        int col = wc + ni * 16 + lr;
        float bv = bias[col];
#pragma unroll
        for (int mi = 0; mi < 4; ++mi) {
#pragma unroll
            for (int r = 0; r < 4; ++r) {
                int row = row0 + wr + mi * 16 + lk * 4 + r;
                if (row < n) {
                    float v = acc[mi][ni][r] + bv;
                    if (relu) v = fmaxf(v, 0.f);
                    if (write_bf) obf[(size_t)row * 128 + col] = f2bf(v);
                    else          of32[(size_t)row * 128 + col] = v;
                }
            }
        }
    }
}

// -------------------- launch --------------------

extern "C" void kernel_launch(void* const* d_in, const int* in_sizes, int n_in,
                              void* d_out, int out_size, void* d_ws, size_t ws_size,
                              hipStream_t stream) {
    const int*   entity     = (const int*)d_in[0];
    const int*   edge_index = (const int*)d_in[1];
    const int*   edge_type  = (const int*)d_in[2];
    const float* edge_norm  = (const float*)d_in[3];
    const float* emb        = (const float*)d_in[4];
    const float* basis1     = (const float*)d_in[5];
    const float* att1       = (const float*)d_in[6];
    const float* root1      = (const float*)d_in[7];
    const float* bias1      = (const float*)d_in[8];
    const float* basis2     = (const float*)d_in[9];
    const float* att2       = (const float*)d_in[10];
    const float* root2      = (const float*)d_in[11];
    const float* bias2      = (const float*)d_in[12];
    float* out = (float*)d_out;

    const int N = in_sizes[0];
    const int E = in_sizes[2];
    const int* src = edge_index;
    const int* dst = edge_index + E;

    size_t ND = (size_t)N * D;
    char* wp = (char*)d_ws;
    int nb = (N + SCAN_B - 1) / SCAN_B;

    size_t off = 0;
    u16*    Zbf      = (u16*)(wp + off);   off += ND * 8;            // N*512 bf16
    u16*    xbf0     = (u16*)(wp + off);   off += ND * 2;            // N*128 bf16
    u16*    Wt       = (u16*)(wp + off);   off += (size_t)128 * 1280 * 2;
    float4* csr_coef = (float4*)(wp + off); off += (size_t)E * 16;
    int2*   csr_se   = (int2*)(wp + off);  off += (size_t)E * 8;
    int*    deg      = (int*)(wp + off);   off += (size_t)N * 4;
    int*    fill     = (int*)(wp + off);   off += (size_t)N * 4;
    float*  inv      = (float*)(wp + off); off += (size_t)N * 4;
    int*    row_start= (int*)(wp + off);   off += (size_t)(N + 1) * 4;
    int*    bsum     = (int*)(wp + off);   off += (size_t)(nb + 1) * 4;
    size_t need = off;

    if (ws_size < need) {
        hipMemsetAsync(d_out, 0, (size_t)out_size * sizeof(float), stream);
        return;
    }

    u16* xbf1 = (u16*)d_out;   // bf16 scratch inside d_out; overwritten by final fp32 GEMM

    int eblk = (E + 255) / 256;
    int ablk = (N + 7) / 8;
    int gblk = (N * 32 + 255) / 256;
    int mblk = (N + BMP - 1) / BMP;
    int wblk = (640 * 128 + 255) / 256;
    int nblk256 = (N + 255) / 256;

    // ---- CSR build (once) ----
    hipMemsetAsync(deg, 0, (size_t)N * 4, stream);
    degree_int_kernel<<<eblk, 256, 0, stream>>>(dst, deg, E);
    scan1_kernel<<<nb, 256, 0, stream>>>(deg, row_start, bsum, N);
    scan2_kernel<<<1, 256, 0, stream>>>(bsum, nb);
    scan3_kernel<<<nblk256, 256, 0, stream>>>(deg, bsum, row_start, inv, N, E);
    hipMemsetAsync(fill, 0, (size_t)N * 4, stream);
    fill_kernel<<<eblk, 256, 0, stream>>>(src, dst, row_start, fill, csr_se, E);
    coef_kernel<<<eblk, 256, 0, stream>>>(csr_se, edge_type, edge_norm, att1, csr_coef, E);
    tobf_gather_kernel<<<gblk, 256, 0, stream>>>(entity, emb, xbf0, N);
    wprep_kernel<<<wblk, 256, 0, stream>>>(basis1, root1, Wt);

    // ---- layer 1: xbf0 -> xbf1 ----
    agg_kernel<<<ablk, 256, 0, stream>>>(row_start, deg, inv, csr_se, csr_coef, xbf0, Zbf, N);
    mfma_gemm_kernel<<<mblk, 512, 0, stream>>>(Zbf, xbf0, Wt, bias1, 0, 1, xbf1, nullptr, N);

    // ---- layer 2: xbf1 -> xbf0 (relu) ----
    agg_kernel<<<ablk, 256, 0, stream>>>(row_start, deg, inv, csr_se, csr_coef, xbf1, Zbf, N);
    mfma_gemm_kernel<<<mblk, 512, 0, stream>>>(Zbf, xbf1, Wt, bias1, 1, 1, xbf0, nullptr, N);

    // ---- layer 3: new coef (att2) + new weights; xbf0 -> out (fp32) ----
    coef_kernel<<<eblk, 256, 0, stream>>>(csr_se, edge_type, edge_norm, att2, csr_coef, E);
    wprep_kernel<<<wblk, 256, 0, stream>>>(basis2, root2, Wt);
    agg_kernel<<<ablk, 256, 0, stream>>>(row_start, deg, inv, csr_se, csr_coef, xbf0, Zbf, N);
    mfma_gemm_kernel<<<mblk, 512, 0, stream>>>(Zbf, xbf0, Wt, bias2, 0, 0, nullptr, out, N);
}

// Round 13
// 463.089 us; speedup vs baseline: 1.1187x; 1.0929x over previous
//
#include <hip/hip_runtime.h>

#define D 128
#define NB 4
#define BM2 256
#define SCAN_B 1024

typedef unsigned short u16;
typedef unsigned int u32;
using bf16x8 = __attribute__((ext_vector_type(8))) short;
using f32x4  = __attribute__((ext_vector_type(4))) float;

__device__ __forceinline__ float bf2f(u16 u) {
    union { u32 i; float f; } v; v.i = ((u32)u) << 16; return v.f;
}
__device__ __forceinline__ u16 f2bf(float f) {
    union { float ff; u32 i; } v; v.ff = f;
    u32 r = v.i + 0x7fffu + ((v.i >> 16) & 1u);   // RNE
    return (u16)(r >> 16);
}

// async 16B global -> LDS (wave-uniform lds base; lane i writes base + i*16)
__device__ __forceinline__ void async16(void* lds, const void* g) {
    __builtin_amdgcn_global_load_lds(
        (const __attribute__((address_space(1))) unsigned int*)g,
        (__attribute__((address_space(3))) unsigned int*)lds,
        16, 0, 0);
}

// -------------------- CSR build --------------------

__global__ __launch_bounds__(256) void degree_int_kernel(const int* __restrict__ dst,
                                                         int* __restrict__ deg, int E) {
    int e = blockIdx.x * 256 + threadIdx.x;
    if (e < E) atomicAdd(&deg[dst[e]], 1);
}

__global__ __launch_bounds__(256) void scan1_kernel(const int* __restrict__ deg,
                                                    int* __restrict__ row_start,
                                                    int* __restrict__ bsum, int n) {
    __shared__ int tsum[256];
    int base = blockIdx.x * SCAN_B;
    int t = threadIdx.x;
    int v[4];
    int s = 0;
#pragma unroll
    for (int i = 0; i < 4; ++i) {
        int idx = base + t * 4 + i;
        v[i] = (idx < n) ? deg[idx] : 0;
        s += v[i];
    }
    tsum[t] = s;
    __syncthreads();
    for (int off = 1; off < 256; off <<= 1) {
        int x = (t >= off) ? tsum[t - off] : 0;
        __syncthreads();
        tsum[t] += x;
        __syncthreads();
    }
    int run = tsum[t] - s;
#pragma unroll
    for (int i = 0; i < 4; ++i) {
        int idx = base + t * 4 + i;
        if (idx < n) row_start[idx] = run;
        run += v[i];
    }
    if (t == 255) bsum[blockIdx.x] = tsum[255];
}

__global__ __launch_bounds__(256) void scan2_kernel(int* __restrict__ bsum, int nb) {
    __shared__ int buf[256];
    __shared__ int carry_s;
    if (threadIdx.x == 0) carry_s = 0;
    __syncthreads();
    for (int base = 0; base < nb; base += 256) {
        int i = base + threadIdx.x;
        int v = (i < nb) ? bsum[i] : 0;
        buf[threadIdx.x] = v;
        __syncthreads();
        for (int off = 1; off < 256; off <<= 1) {
            int x = (threadIdx.x >= (unsigned)off) ? buf[threadIdx.x - off] : 0;
            __syncthreads();
            buf[threadIdx.x] += x;
            __syncthreads();
        }
        if (i < nb) bsum[i] = carry_s + buf[threadIdx.x] - v;
        __syncthreads();
        if (threadIdx.x == 0) carry_s += buf[255];
        __syncthreads();
    }
}

__global__ __launch_bounds__(256) void scan3_kernel(const int* __restrict__ deg,
                                                    const int* __restrict__ bsum,
                                                    int* __restrict__ row_start,
                                                    float* __restrict__ inv, int n, int E) {
    int i = blockIdx.x * 256 + threadIdx.x;
    if (i < n) {
        row_start[i] += bsum[i >> 10];
        inv[i] = 1.0f / fmaxf((float)deg[i], 1.0f);
    }
    if (i == 0) row_start[n] = E;
}

// fill: CSR permutation only — ONE scattered 8B store per edge (src, eid packed)
__global__ __launch_bounds__(256) void fill_kernel(
    const int* __restrict__ src, const int* __restrict__ dst,
    const int* __restrict__ row_start, int* __restrict__ fill,
    int2* __restrict__ csr_se, int E)
{
    int e = blockIdx.x * 256 + threadIdx.x;
    if (e >= E) return;
    int d0 = dst[e];
    int pos = row_start[d0] + atomicAdd(&fill[d0], 1);
    csr_se[pos] = make_int2(src[e], e);
}

// coef: linear read of csr_se, random 4B reads (L2-resident), COALESCED write
__global__ __launch_bounds__(256) void coef_kernel(
    const int2* __restrict__ csr_se, const int* __restrict__ etype,
    const float* __restrict__ norm, const float* __restrict__ att,
    float4* __restrict__ csr_coef, int E)
{
    int p = blockIdx.x * 256 + threadIdx.x;
    if (p >= E) return;
    int e = csr_se[p].y;
    float nm = norm[e];
    float4 a = ((const float4*)att)[etype[e]];
    csr_coef[p] = make_float4(a.x * nm, a.y * nm, a.z * nm, a.w * nm);
}

// -------------------- gather emb -> bf16 x0 --------------------

__global__ __launch_bounds__(256) void tobf_gather_kernel(const int* __restrict__ entity,
                                                          const float* __restrict__ emb,
                                                          u16* __restrict__ xbf, int n) {
    int idx = blockIdx.x * 256 + threadIdx.x;
    if (idx >= n * 32) return;
    int row = idx >> 5, c = idx & 31;
    float4 v = ((const float4*)emb)[(size_t)entity[row] * 32 + c];
    ushort4 o;
    o.x = f2bf(v.x); o.y = f2bf(v.y); o.z = f2bf(v.z); o.w = f2bf(v.w);
    ((ushort4*)xbf)[idx] = o;
}

// -------------------- CSR aggregation (8x/4x unrolled gather MLP) ----------
// (proven-passing form from rounds 10/11 benches)
#define AGG_BODY(UJ)                                                            \
    {                                                                           \
        float4 c = c_[UJ];                                                      \
        float4 xv;                                                              \
        xv.x = bf2f(u_[UJ].x); xv.y = bf2f(u_[UJ].y);                           \
        xv.z = bf2f(u_[UJ].z); xv.w = bf2f(u_[UJ].w);                           \
        z0.x += c.x * xv.x; z0.y += c.x * xv.y; z0.z += c.x * xv.z; z0.w += c.x * xv.w; \
        z1.x += c.y * xv.x; z1.y += c.y * xv.y; z1.z += c.y * xv.z; z1.w += c.y * xv.w; \
        z2.x += c.z * xv.x; z2.y += c.z * xv.y; z2.z += c.z * xv.z; z2.w += c.z * xv.w; \
        z3.x += c.w * xv.x; z3.y += c.w * xv.y; z3.z += c.w * xv.z; z3.w += c.w * xv.w; \
    }

__global__ __launch_bounds__(256) void agg_kernel(
    const int* __restrict__ row_start, const int* __restrict__ deg,
    const float* __restrict__ inv, const int2* __restrict__ csr_se,
    const float4* __restrict__ csr_coef, const u16* __restrict__ xbf,
    u16* __restrict__ Zbf, int n)
{
    int nd = blockIdx.x * 8 + (threadIdx.x >> 5);
    if (nd >= n) return;
    int q = threadIdx.x & 31;
    int s0 = row_start[nd];
    int dg = deg[nd];
    float4 z0 = make_float4(0.f,0.f,0.f,0.f), z1 = z0, z2 = z0, z3 = z0;

    int i = 0;
    for (; i + 8 <= dg; i += 8) {
        int s_[8]; float4 c_[8]; ushort4 u_[8];
#pragma unroll
        for (int j = 0; j < 8; ++j) s_[j] = csr_se[s0 + i + j].x;
#pragma unroll
        for (int j = 0; j < 8; ++j) c_[j] = csr_coef[s0 + i + j];
#pragma unroll
        for (int j = 0; j < 8; ++j) u_[j] = ((const ushort4*)xbf)[(size_t)s_[j] * 32 + q];
#pragma unroll
        for (int j = 0; j < 8; ++j) AGG_BODY(j)
    }
    for (; i + 4 <= dg; i += 4) {
        int s_[4]; float4 c_[4]; ushort4 u_[4];
#pragma unroll
        for (int j = 0; j < 4; ++j) s_[j] = csr_se[s0 + i + j].x;
#pragma unroll
        for (int j = 0; j < 4; ++j) c_[j] = csr_coef[s0 + i + j];
#pragma unroll
        for (int j = 0; j < 4; ++j) u_[j] = ((const ushort4*)xbf)[(size_t)s_[j] * 32 + q];
#pragma unroll
        for (int j = 0; j < 4; ++j) AGG_BODY(j)
    }
    for (; i < dg; ++i) {
        int s_[1]; float4 c_[1]; ushort4 u_[1];
        s_[0] = csr_se[s0 + i].x;
        c_[0] = csr_coef[s0 + i];
        u_[0] = ((const ushort4*)xbf)[(size_t)s_[0] * 32 + q];
        AGG_BODY(0)
    }

    float iv = inv[nd];
    ushort4* zp = ((ushort4*)Zbf) + (size_t)nd * 128;
    ushort4 o;
    o.x = f2bf(z0.x * iv); o.y = f2bf(z0.y * iv); o.z = f2bf(z0.z * iv); o.w = f2bf(z0.w * iv);
    zp[q] = o;
    o.x = f2bf(z1.x * iv); o.y = f2bf(z1.y * iv); o.z = f2bf(z1.z * iv); o.w = f2bf(z1.w * iv);
    zp[32 + q] = o;
    o.x = f2bf(z2.x * iv); o.y = f2bf(z2.y * iv); o.z = f2bf(z2.z * iv); o.w = f2bf(z2.w * iv);
    zp[64 + q] = o;
    o.x = f2bf(z3.x * iv); o.y = f2bf(z3.y * iv); o.z = f2bf(z3.z * iv); o.w = f2bf(z3.w * iv);
    zp[96 + q] = o;
}

// -------------------- weight prep: transpose + hi/lo bf16 split --------------------
__global__ __launch_bounds__(256) void wprep_kernel(
    const float* __restrict__ basis, const float* __restrict__ root,
    u16* __restrict__ Wt)
{
    int idx = blockIdx.x * 256 + threadIdx.x;  // over 640*128
    if (idx >= 640 * 128) return;
    int k = idx >> 7, nn = idx & 127;
    float w = (k < 512) ? basis[(size_t)k * 128 + nn] : root[(size_t)(k - 512) * 128 + nn];
    u16 hi = f2bf(w);
    float lo = w - bf2f(hi);
    Wt[(size_t)nn * 1280 + k] = hi;
    Wt[(size_t)nn * 1280 + 640 + k] = f2bf(lo);
}

// -------------------- MFMA layer GEMM (proven round-7 structure: 60 us) ------
// out[M][128] = [Zbf | xbf](M x 640 bf16) @ W(640 x 128, hi+lo bf16) + bias
__global__ __launch_bounds__(512) void mfma_gemm_kernel(
    const u16* __restrict__ Zbf, const u16* __restrict__ xbf,
    const u16* __restrict__ Wt, const float* __restrict__ bias,
    int relu, int write_bf, u16* __restrict__ obf, float* __restrict__ of32, int n)
{
    __shared__ u16 As[BM2 * 64];   // 32 KB
    __shared__ u16 Bs[128 * 64];   // 16 KB

    const int tid  = threadIdx.x;
    const int row0 = blockIdx.x * BM2;
    const int lane = tid & 63;
    const int w    = tid >> 6;        // 0..7
    const int wr   = (w >> 1) * 64;   // 0,64,128,192
    const int wc   = (w & 1) * 64;    // 0,64
    const int lr   = lane & 15;
    const int lk   = lane >> 4;

    const int srow = lane >> 3;                       // r & 7 for staging
    const int sswz = ((lane & 7) * 16) ^ (srow << 4); // swizzled byte within row

    f32x4 zero = {0.f, 0.f, 0.f, 0.f};
    f32x4 acc[4][4];
#pragma unroll
    for (int mi = 0; mi < 4; ++mi)
#pragma unroll
        for (int ni = 0; ni < 4; ++ni) acc[mi][ni] = zero;

    for (int s = 0; s < 20; ++s) {
        const int ac = s >> 1;                    // A chunk 0..9
        const int wk = (s & 1) * 640 + ac * 64;   // Wt k-offset (hi then lo)
        __syncthreads();
        if ((s & 1) == 0) {
#pragma unroll
            for (int j = 0; j < 4; ++j) {
                int r    = (w << 5) + (j << 3) + srow;
                int grow = row0 + r;
                const u16* gp = (ac < 8)
                    ? (Zbf + (size_t)grow * 512 + ac * 64)
                    : (xbf + (size_t)grow * 128 + (ac - 8) * 64);
                async16((char*)As + (((w << 5) + (j << 3)) << 7),
                        (const char*)gp + sswz);
            }
        }
#pragma unroll
        for (int j = 0; j < 2; ++j) {
            int rr = (w << 4) + (j << 3) + srow;
            const u16* gp = Wt + (size_t)rr * 1280 + wk;
            async16((char*)Bs + (((w << 4) + (j << 3)) << 7),
                    (const char*)gp + sswz);
        }
        __syncthreads();

#pragma unroll
        for (int kh = 0; kh < 2; ++kh) {
            const int kb = (kh * 64 + lk * 16) ^ ((lr & 7) << 4);
            bf16x8 af[4], bfr[4];
#pragma unroll
            for (int mi = 0; mi < 4; ++mi)
                af[mi] = *(const bf16x8*)((const char*)As + ((wr + mi * 16 + lr) << 7) + kb);
#pragma unroll
            for (int ni = 0; ni < 4; ++ni)
                bfr[ni] = *(const bf16x8*)((const char*)Bs + ((wc + ni * 16 + lr) << 7) + kb);
#pragma unroll
            for (int mi = 0; mi < 4; ++mi)
#pragma unroll
                for (int ni = 0; ni < 4; ++ni)
                    acc[mi][ni] = __builtin_amdgcn_mfma_f32_16x16x32_bf16(
                        af[mi], bfr[ni], acc[mi][ni], 0, 0, 0);
        }
    }

    // epilogue: C/D layout col = lane&15, row = (lane>>4)*4 + reg
#pragma unroll
    for (int ni = 0; ni < 4; ++ni) {
        int col = wc + ni * 16 + lr;
        float bv = bias[col];
#pragma unroll
        for (int mi = 0; mi < 4; ++mi) {
#pragma unroll
            for (int r = 0; r < 4; ++r) {
                int row = row0 + wr + mi * 16 + lk * 4 + r;
                if (row < n) {
                    float v = acc[mi][ni][r] + bv;
                    if (relu) v = fmaxf(v, 0.f);
                    if (write_bf) obf[(size_t)row * 128 + col] = f2bf(v);
                    else          of32[(size_t)row * 128 + col] = v;
                }
            }
        }
    }
}

// -------------------- launch --------------------

extern "C" void kernel_launch(void* const* d_in, const int* in_sizes, int n_in,
                              void* d_out, int out_size, void* d_ws, size_t ws_size,
                              hipStream_t stream) {
    const int*   entity     = (const int*)d_in[0];
    const int*   edge_index = (const int*)d_in[1];
    const int*   edge_type  = (const int*)d_in[2];
    const float* edge_norm  = (const float*)d_in[3];
    const float* emb        = (const float*)d_in[4];
    const float* basis1     = (const float*)d_in[5];
    const float* att1       = (const float*)d_in[6];
    const float* root1      = (const float*)d_in[7];
    const float* bias1      = (const float*)d_in[8];
    const float* basis2     = (const float*)d_in[9];
    const float* att2       = (const float*)d_in[10];
    const float* root2      = (const float*)d_in[11];
    const float* bias2      = (const float*)d_in[12];
    float* out = (float*)d_out;

    const int N = in_sizes[0];
    const int E = in_sizes[2];
    const int* src = edge_index;
    const int* dst = edge_index + E;

    size_t ND = (size_t)N * D;
    char* wp = (char*)d_ws;
    int nb = (N + SCAN_B - 1) / SCAN_B;

    size_t off = 0;
    u16*    Zbf      = (u16*)(wp + off);   off += ND * 8;            // N*512 bf16
    u16*    xbf0     = (u16*)(wp + off);   off += ND * 2;            // N*128 bf16
    u16*    Wt       = (u16*)(wp + off);   off += (size_t)128 * 1280 * 2;
    float4* csr_coef = (float4*)(wp + off); off += (size_t)E * 16;
    int2*   csr_se   = (int2*)(wp + off);  off += (size_t)E * 8;
    int*    deg      = (int*)(wp + off);   off += (size_t)N * 4;
    int*    fill     = (int*)(wp + off);   off += (size_t)N * 4;
    float*  inv      = (float*)(wp + off); off += (size_t)N * 4;
    int*    row_start= (int*)(wp + off);   off += (size_t)(N + 1) * 4;
    int*    bsum     = (int*)(wp + off);   off += (size_t)(nb + 1) * 4;
    size_t need = off;

    if (ws_size < need) {
        hipMemsetAsync(d_out, 0, (size_t)out_size * sizeof(float), stream);
        return;
    }

    u16* xbf1 = (u16*)d_out;   // bf16 scratch inside d_out; overwritten by final fp32 GEMM

    int eblk = (E + 255) / 256;
    int ablk = (N + 7) / 8;
    int gblk = (N * 32 + 255) / 256;
    int mblk = (N + BM2 - 1) / BM2;
    int wblk = (640 * 128 + 255) / 256;
    int nblk256 = (N + 255) / 256;

    // ---- CSR build (once) ----
    hipMemsetAsync(deg, 0, (size_t)N * 4, stream);
    degree_int_kernel<<<eblk, 256, 0, stream>>>(dst, deg, E);
    scan1_kernel<<<nb, 256, 0, stream>>>(deg, row_start, bsum, N);
    scan2_kernel<<<1, 256, 0, stream>>>(bsum, nb);
    scan3_kernel<<<nblk256, 256, 0, stream>>>(deg, bsum, row_start, inv, N, E);
    hipMemsetAsync(fill, 0, (size_t)N * 4, stream);
    fill_kernel<<<eblk, 256, 0, stream>>>(src, dst, row_start, fill, csr_se, E);
    coef_kernel<<<eblk, 256, 0, stream>>>(csr_se, edge_type, edge_norm, att1, csr_coef, E);
    tobf_gather_kernel<<<gblk, 256, 0, stream>>>(entity, emb, xbf0, N);
    wprep_kernel<<<wblk, 256, 0, stream>>>(basis1, root1, Wt);

    // ---- layer 1: xbf0 -> xbf1 ----
    agg_kernel<<<ablk, 256, 0, stream>>>(row_start, deg, inv, csr_se, csr_coef, xbf0, Zbf, N);
    mfma_gemm_kernel<<<mblk, 512, 0, stream>>>(Zbf, xbf0, Wt, bias1, 0, 1, xbf1, nullptr, N);

    // ---- layer 2: xbf1 -> xbf0 (relu) ----
    agg_kernel<<<ablk, 256, 0, stream>>>(row_start, deg, inv, csr_se, csr_coef, xbf1, Zbf, N);
    mfma_gemm_kernel<<<mblk, 512, 0, stream>>>(Zbf, xbf1, Wt, bias1, 1, 1, xbf0, nullptr, N);

    // ---- layer 3: new coef (att2) + new weights; xbf0 -> out (fp32) ----
    coef_kernel<<<eblk, 256, 0, stream>>>(csr_se, edge_type, edge_norm, att2, csr_coef, E);
    wprep_kernel<<<wblk, 256, 0, stream>>>(basis2, root2, Wt);
    agg_kernel<<<ablk, 256, 0, stream>>>(row_start, deg, inv, csr_se, csr_coef, xbf0, Zbf, N);
    mfma_gemm_kernel<<<mblk, 512, 0, stream>>>(Zbf, xbf0, Wt, bias2, 0, 0, nullptr, out, N);
}

// Round 14
// 460.868 us; speedup vs baseline: 1.1241x; 1.0048x over previous
//
#include <hip/hip_runtime.h>

#define D 128
#define NB 4
#define BM2 256
#define SCAN_B 1024
#define FILL_PASSES 4

typedef unsigned short u16;
typedef unsigned int u32;
using bf16x8 = __attribute__((ext_vector_type(8))) short;
using f32x4  = __attribute__((ext_vector_type(4))) float;

__device__ __forceinline__ float bf2f(u16 u) {
    union { u32 i; float f; } v; v.i = ((u32)u) << 16; return v.f;
}
__device__ __forceinline__ u16 f2bf(float f) {
    union { float ff; u32 i; } v; v.ff = f;
    u32 r = v.i + 0x7fffu + ((v.i >> 16) & 1u);   // RNE
    return (u16)(r >> 16);
}

// async 16B global -> LDS (wave-uniform lds base; lane i writes base + i*16)
__device__ __forceinline__ void async16(void* lds, const void* g) {
    __builtin_amdgcn_global_load_lds(
        (const __attribute__((address_space(1))) unsigned int*)g,
        (__attribute__((address_space(3))) unsigned int*)lds,
        16, 0, 0);
}

// -------------------- CSR build --------------------

__global__ __launch_bounds__(256) void degree_int_kernel(const int* __restrict__ dst,
                                                         int* __restrict__ deg, int E) {
    int e = blockIdx.x * 256 + threadIdx.x;
    if (e < E) atomicAdd(&deg[dst[e]], 1);
}

__global__ __launch_bounds__(256) void scan1_kernel(const int* __restrict__ deg,
                                                    int* __restrict__ row_start,
                                                    int* __restrict__ bsum, int n) {
    __shared__ int tsum[256];
    int base = blockIdx.x * SCAN_B;
    int t = threadIdx.x;
    int v[4];
    int s = 0;
#pragma unroll
    for (int i = 0; i < 4; ++i) {
        int idx = base + t * 4 + i;
        v[i] = (idx < n) ? deg[idx] : 0;
        s += v[i];
    }
    tsum[t] = s;
    __syncthreads();
    for (int off = 1; off < 256; off <<= 1) {
        int x = (t >= off) ? tsum[t - off] : 0;
        __syncthreads();
        tsum[t] += x;
        __syncthreads();
    }
    int run = tsum[t] - s;
#pragma unroll
    for (int i = 0; i < 4; ++i) {
        int idx = base + t * 4 + i;
        if (idx < n) row_start[idx] = run;
        run += v[i];
    }
    if (t == 255) bsum[blockIdx.x] = tsum[255];
}

__global__ __launch_bounds__(256) void scan2_kernel(int* __restrict__ bsum, int nb) {
    __shared__ int buf[256];
    __shared__ int carry_s;
    if (threadIdx.x == 0) carry_s = 0;
    __syncthreads();
    for (int base = 0; base < nb; base += 256) {
        int i = base + threadIdx.x;
        int v = (i < nb) ? bsum[i] : 0;
        buf[threadIdx.x] = v;
        __syncthreads();
        for (int off = 1; off < 256; off <<= 1) {
            int x = (threadIdx.x >= (unsigned)off) ? buf[threadIdx.x - off] : 0;
            __syncthreads();
            buf[threadIdx.x] += x;
            __syncthreads();
        }
        if (i < nb) bsum[i] = carry_s + buf[threadIdx.x] - v;
        __syncthreads();
        if (threadIdx.x == 0) carry_s += buf[255];
        __syncthreads();
    }
}

__global__ __launch_bounds__(256) void scan3_kernel(const int* __restrict__ deg,
                                                    const int* __restrict__ bsum,
                                                    int* __restrict__ row_start,
                                                    float* __restrict__ inv, int n, int E) {
    int i = blockIdx.x * 256 + threadIdx.x;
    if (i < n) {
        row_start[i] += bsum[i >> 10];
        inv[i] = 1.0f / fmaxf((float)deg[i], 1.0f);
    }
    if (i == 0) row_start[n] = E;
}

// fill: CSR permutation, binned into FILL_PASSES dst-range passes so the
// scattered csr_se writes of one pass stay in a small L2-resident window
// (kills the one-line-writeback-per-edge amplification). Block b handles
// edge chunk (b % nchunks) for pass (b / nchunks); any execution order is
// correct (passes touch disjoint dst ranges -> disjoint pos ranges).
__global__ __launch_bounds__(256) void fill_kernel(
    const int* __restrict__ src, const int* __restrict__ dst,
    const int* __restrict__ row_start, int* __restrict__ fill,
    int2* __restrict__ csr_se, int E, int nchunks, int chunk)
{
    int b = blockIdx.x;
    int p = b / nchunks;
    int e = (b % nchunks) * 256 + threadIdx.x;
    if (e >= E) return;
    int d0 = dst[e];
    int lo = p * chunk;
    if (d0 < lo || d0 >= lo + chunk) return;
    int pos = row_start[d0] + atomicAdd(&fill[d0], 1);
    csr_se[pos] = make_int2(src[e], e);
}

// coef: linear read of csr_se, random 4B reads (L2-resident), COALESCED write
__global__ __launch_bounds__(256) void coef_kernel(
    const int2* __restrict__ csr_se, const int* __restrict__ etype,
    const float* __restrict__ norm, const float* __restrict__ att,
    float4* __restrict__ csr_coef, int E)
{
    int p = blockIdx.x * 256 + threadIdx.x;
    if (p >= E) return;
    int e = csr_se[p].y;
    float nm = norm[e];
    float4 a = ((const float4*)att)[etype[e]];
    csr_coef[p] = make_float4(a.x * nm, a.y * nm, a.z * nm, a.w * nm);
}

// -------------------- gather emb -> bf16 x0 --------------------

__global__ __launch_bounds__(256) void tobf_gather_kernel(const int* __restrict__ entity,
                                                          const float* __restrict__ emb,
                                                          u16* __restrict__ xbf, int n) {
    int idx = blockIdx.x * 256 + threadIdx.x;
    if (idx >= n * 32) return;
    int row = idx >> 5, c = idx & 31;
    float4 v = ((const float4*)emb)[(size_t)entity[row] * 32 + c];
    ushort4 o;
    o.x = f2bf(v.x); o.y = f2bf(v.y); o.z = f2bf(v.z); o.w = f2bf(v.w);
    ((ushort4*)xbf)[idx] = o;
}

// -------------------- CSR aggregation (8x/4x unrolled gather MLP) ----------
#define AGG_BODY(UJ)                                                            \
    {                                                                           \
        float4 c = c_[UJ];                                                      \
        float4 xv;                                                              \
        xv.x = bf2f(u_[UJ].x); xv.y = bf2f(u_[UJ].y);                           \
        xv.z = bf2f(u_[UJ].z); xv.w = bf2f(u_[UJ].w);                           \
        z0.x += c.x * xv.x; z0.y += c.x * xv.y; z0.z += c.x * xv.z; z0.w += c.x * xv.w; \
        z1.x += c.y * xv.x; z1.y += c.y * xv.y; z1.z += c.y * xv.z; z1.w += c.y * xv.w; \
        z2.x += c.z * xv.x; z2.y += c.z * xv.y; z2.z += c.z * xv.z; z2.w += c.z * xv.w; \
        z3.x += c.w * xv.x; z3.y += c.w * xv.y; z3.z += c.w * xv.z; z3.w += c.w * xv.w; \
    }

__global__ __launch_bounds__(256) void agg_kernel(
    const int* __restrict__ row_start, const int* __restrict__ deg,
    const float* __restrict__ inv, const int2* __restrict__ csr_se,
    const float4* __restrict__ csr_coef, const u16* __restrict__ xbf,
    u16* __restrict__ Zbf, int n)
{
    int nd = blockIdx.x * 8 + (threadIdx.x >> 5);
    if (nd >= n) return;
    int q = threadIdx.x & 31;
    int s0 = row_start[nd];
    int dg = deg[nd];
    float4 z0 = make_float4(0.f,0.f,0.f,0.f), z1 = z0, z2 = z0, z3 = z0;

    int i = 0;
    for (; i + 8 <= dg; i += 8) {
        int s_[8]; float4 c_[8]; ushort4 u_[8];
#pragma unroll
        for (int j = 0; j < 8; ++j) s_[j] = csr_se[s0 + i + j].x;
#pragma unroll
        for (int j = 0; j < 8; ++j) c_[j] = csr_coef[s0 + i + j];
#pragma unroll
        for (int j = 0; j < 8; ++j) u_[j] = ((const ushort4*)xbf)[(size_t)s_[j] * 32 + q];
#pragma unroll
        for (int j = 0; j < 8; ++j) AGG_BODY(j)
    }
    for (; i + 4 <= dg; i += 4) {
        int s_[4]; float4 c_[4]; ushort4 u_[4];
#pragma unroll
        for (int j = 0; j < 4; ++j) s_[j] = csr_se[s0 + i + j].x;
#pragma unroll
        for (int j = 0; j < 4; ++j) c_[j] = csr_coef[s0 + i + j];
#pragma unroll
        for (int j = 0; j < 4; ++j) u_[j] = ((const ushort4*)xbf)[(size_t)s_[j] * 32 + q];
#pragma unroll
        for (int j = 0; j < 4; ++j) AGG_BODY(j)
    }
    for (; i < dg; ++i) {
        int s_[1]; float4 c_[1]; ushort4 u_[1];
        s_[0] = csr_se[s0 + i].x;
        c_[0] = csr_coef[s0 + i];
        u_[0] = ((const ushort4*)xbf)[(size_t)s_[0] * 32 + q];
        AGG_BODY(0)
    }

    float iv = inv[nd];
    ushort4* zp = ((ushort4*)Zbf) + (size_t)nd * 128;
    ushort4 o;
    o.x = f2bf(z0.x * iv); o.y = f2bf(z0.y * iv); o.z = f2bf(z0.z * iv); o.w = f2bf(z0.w * iv);
    zp[q] = o;
    o.x = f2bf(z1.x * iv); o.y = f2bf(z1.y * iv); o.z = f2bf(z1.z * iv); o.w = f2bf(z1.w * iv);
    zp[32 + q] = o;
    o.x = f2bf(z2.x * iv); o.y = f2bf(z2.y * iv); o.z = f2bf(z2.z * iv); o.w = f2bf(z2.w * iv);
    zp[64 + q] = o;
    o.x = f2bf(z3.x * iv); o.y = f2bf(z3.y * iv); o.z = f2bf(z3.z * iv); o.w = f2bf(z3.w * iv);
    zp[96 + q] = o;
}

// -------------------- weight prep: transpose + hi/lo bf16 split --------------------
__global__ __launch_bounds__(256) void wprep_kernel(
    const float* __restrict__ basis, const float* __restrict__ root,
    u16* __restrict__ Wt)
{
    int idx = blockIdx.x * 256 + threadIdx.x;  // over 640*128
    if (idx >= 640 * 128) return;
    int k = idx >> 7, nn = idx & 127;
    float w = (k < 512) ? basis[(size_t)k * 128 + nn] : root[(size_t)(k - 512) * 128 + nn];
    u16 hi = f2bf(w);
    float lo = w - bf2f(hi);
    Wt[(size_t)nn * 1280 + k] = hi;
    Wt[(size_t)nn * 1280 + 640 + k] = f2bf(lo);
}

// -------------------- MFMA layer GEMM (proven round-7 structure: 60 us) ------
// out[M][128] = [Zbf | xbf](M x 640 bf16) @ W(640 x 128, hi+lo bf16) + bias
__global__ __launch_bounds__(512) void mfma_gemm_kernel(
    const u16* __restrict__ Zbf, const u16* __restrict__ xbf,
    const u16* __restrict__ Wt, const float* __restrict__ bias,
    int relu, int write_bf, u16* __restrict__ obf, float* __restrict__ of32, int n)
{
    __shared__ u16 As[BM2 * 64];   // 32 KB
    __shared__ u16 Bs[128 * 64];   // 16 KB

    const int tid  = threadIdx.x;
    const int row0 = blockIdx.x * BM2;
    const int lane = tid & 63;
    const int w    = tid >> 6;        // 0..7
    const int wr   = (w >> 1) * 64;   // 0,64,128,192
    const int wc   = (w & 1) * 64;    // 0,64
    const int lr   = lane & 15;
    const int lk   = lane >> 4;

    const int srow = lane >> 3;                       // r & 7 for staging
    const int sswz = ((lane & 7) * 16) ^ (srow << 4); // swizzled byte within row

    f32x4 zero = {0.f, 0.f, 0.f, 0.f};
    f32x4 acc[4][4];
#pragma unroll
    for (int mi = 0; mi < 4; ++mi)
#pragma unroll
        for (int ni = 0; ni < 4; ++ni) acc[mi][ni] = zero;

    for (int s = 0; s < 20; ++s) {
        const int ac = s >> 1;                    // A chunk 0..9
        const int wk = (s & 1) * 640 + ac * 64;   // Wt k-offset (hi then lo)
        __syncthreads();
        if ((s & 1) == 0) {
#pragma unroll
            for (int j = 0; j < 4; ++j) {
                int r    = (w << 5) + (j << 3) + srow;
                int grow = row0 + r;
                const u16* gp = (ac < 8)
                    ? (Zbf + (size_t)grow * 512 + ac * 64)
                    : (xbf + (size_t)grow * 128 + (ac - 8) * 64);
                async16((char*)As + (((w << 5) + (j << 3)) << 7),
                        (const char*)gp + sswz);
            }
        }
#pragma unroll
        for (int j = 0; j < 2; ++j) {
            int rr = (w << 4) + (j << 3) + srow;
            const u16* gp = Wt + (size_t)rr * 1280 + wk;
            async16((char*)Bs + (((w << 4) + (j << 3)) << 7),
                    (const char*)gp + sswz);
        }
        __syncthreads();

#pragma unroll
        for (int kh = 0; kh < 2; ++kh) {
            const int kb = (kh * 64 + lk * 16) ^ ((lr & 7) << 4);
            bf16x8 af[4], bfr[4];
#pragma unroll
            for (int mi = 0; mi < 4; ++mi)
                af[mi] = *(const bf16x8*)((const char*)As + ((wr + mi * 16 + lr) << 7) + kb);
#pragma unroll
            for (int ni = 0; ni < 4; ++ni)
                bfr[ni] = *(const bf16x8*)((const char*)Bs + ((wc + ni * 16 + lr) << 7) + kb);
#pragma unroll
            for (int mi = 0; mi < 4; ++mi)
#pragma unroll
                for (int ni = 0; ni < 4; ++ni)
                    acc[mi][ni] = __builtin_amdgcn_mfma_f32_16x16x32_bf16(
                        af[mi], bfr[ni], acc[mi][ni], 0, 0, 0);
        }
    }

    // epilogue: C/D layout col = lane&15, row = (lane>>4)*4 + reg
#pragma unroll
    for (int ni = 0; ni < 4; ++ni) {
        int col = wc + ni * 16 + lr;
        float bv = bias[col];
#pragma unroll
        for (int mi = 0; mi < 4; ++mi) {
#pragma unroll
            for (int r = 0; r < 4; ++r) {
                int row = row0 + wr + mi * 16 + lk * 4 + r;
                if (row < n) {
                    float v = acc[mi][ni][r] + bv;
                    if (relu) v = fmaxf(v, 0.f);
                    if (write_bf) obf[(size_t)row * 128 + col] = f2bf(v);
                    else          of32[(size_t)row * 128 + col] = v;
                }
            }
        }
    }
}

// -------------------- launch --------------------

extern "C" void kernel_launch(void* const* d_in, const int* in_sizes, int n_in,
                              void* d_out, int out_size, void* d_ws, size_t ws_size,
                              hipStream_t stream) {
    const int*   entity     = (const int*)d_in[0];
    const int*   edge_index = (const int*)d_in[1];
    const int*   edge_type  = (const int*)d_in[2];
    const float* edge_norm  = (const float*)d_in[3];
    const float* emb        = (const float*)d_in[4];
    const float* basis1     = (const float*)d_in[5];
    const float* att1       = (const float*)d_in[6];
    const float* root1      = (const float*)d_in[7];
    const float* bias1      = (const float*)d_in[8];
    const float* basis2     = (const float*)d_in[9];
    const float* att2       = (const float*)d_in[10];
    const float* root2      = (const float*)d_in[11];
    const float* bias2      = (const float*)d_in[12];
    float* out = (float*)d_out;

    const int N = in_sizes[0];
    const int E = in_sizes[2];
    const int* src = edge_index;
    const int* dst = edge_index + E;

    size_t ND = (size_t)N * D;
    char* wp = (char*)d_ws;
    int nb = (N + SCAN_B - 1) / SCAN_B;

    size_t off = 0;
    u16*    Zbf      = (u16*)(wp + off);   off += ND * 8;            // N*512 bf16
    u16*    xbf0     = (u16*)(wp + off);   off += ND * 2;            // N*128 bf16
    u16*    Wt       = (u16*)(wp + off);   off += (size_t)128 * 1280 * 2;
    float4* csr_coef = (float4*)(wp + off); off += (size_t)E * 16;
    int2*   csr_se   = (int2*)(wp + off);  off += (size_t)E * 8;
    int*    deg      = (int*)(wp + off);   off += (size_t)N * 4;
    int*    fill     = (int*)(wp + off);   off += (size_t)N * 4;
    float*  inv      = (float*)(wp + off); off += (size_t)N * 4;
    int*    row_start= (int*)(wp + off);   off += (size_t)(N + 1) * 4;
    int*    bsum     = (int*)(wp + off);   off += (size_t)(nb + 1) * 4;
    size_t need = off;

    if (ws_size < need) {
        hipMemsetAsync(d_out, 0, (size_t)out_size * sizeof(float), stream);
        return;
    }

    u16* xbf1 = (u16*)d_out;   // bf16 scratch inside d_out; overwritten by final fp32 GEMM

    int eblk = (E + 255) / 256;
    int ablk = (N + 7) / 8;
    int gblk = (N * 32 + 255) / 256;
    int mblk = (N + BM2 - 1) / BM2;
    int wblk = (640 * 128 + 255) / 256;
    int nblk256 = (N + 255) / 256;
    int chunk = (N + FILL_PASSES - 1) / FILL_PASSES;

    // ---- CSR build (once) ----
    hipMemsetAsync(deg, 0, (size_t)N * 4, stream);
    degree_int_kernel<<<eblk, 256, 0, stream>>>(dst, deg, E);
    scan1_kernel<<<nb, 256, 0, stream>>>(deg, row_start, bsum, N);
    scan2_kernel<<<1, 256, 0, stream>>>(bsum, nb);
    scan3_kernel<<<nblk256, 256, 0, stream>>>(deg, bsum, row_start, inv, N, E);
    hipMemsetAsync(fill, 0, (size_t)N * 4, stream);
    fill_kernel<<<eblk * FILL_PASSES, 256, 0, stream>>>(src, dst, row_start, fill,
                                                        csr_se, E, eblk, chunk);
    coef_kernel<<<eblk, 256, 0, stream>>>(csr_se, edge_type, edge_norm, att1, csr_coef, E);
    tobf_gather_kernel<<<gblk, 256, 0, stream>>>(entity, emb, xbf0, N);
    wprep_kernel<<<wblk, 256, 0, stream>>>(basis1, root1, Wt);

    // ---- layer 1: xbf0 -> xbf1 ----
    agg_kernel<<<ablk, 256, 0, stream>>>(row_start, deg, inv, csr_se, csr_coef, xbf0, Zbf, N);
    mfma_gemm_kernel<<<mblk, 512, 0, stream>>>(Zbf, xbf0, Wt, bias1, 0, 1, xbf1, nullptr, N);

    // ---- layer 2: xbf1 -> xbf0 (relu) ----
    agg_kernel<<<ablk, 256, 0, stream>>>(row_start, deg, inv, csr_se, csr_coef, xbf1, Zbf, N);
    mfma_gemm_kernel<<<mblk, 512, 0, stream>>>(Zbf, xbf1, Wt, bias1, 1, 1, xbf0, nullptr, N);

    // ---- layer 3: new coef (att2) + new weights; xbf0 -> out (fp32) ----
    coef_kernel<<<eblk, 256, 0, stream>>>(csr_se, edge_type, edge_norm, att2, csr_coef, E);
    wprep_kernel<<<wblk, 256, 0, stream>>>(basis2, root2, Wt);
    agg_kernel<<<ablk, 256, 0, stream>>>(row_start, deg, inv, csr_se, csr_coef, xbf0, Zbf, N);
    mfma_gemm_kernel<<<mblk, 512, 0, stream>>>(Zbf, xbf0, Wt, bias2, 0, 0, nullptr, out, N);
}